// Round 5
// baseline (3663.158 us; speedup 1.0000x reference)
//
#include <hip/hip_runtime.h>
#include <hip/hip_bf16.h>
#include <math.h>

#define NTOK 16000
#define E    512
#define FFD  2048
#define CBN  4096
#define SEQ  1000
#define NH   8
#define VLD  1008   // Vt padded leading dim (s), multiple of 8

typedef __hip_bfloat16 bf16;
typedef __attribute__((ext_vector_type(8))) short short8;
typedef __attribute__((ext_vector_type(4))) float f32x4;

__device__ __forceinline__ float gelu_f(float v) {
    return 0.5f * v * (1.0f + erff(v * 0.70710678118654752f));
}

__device__ __forceinline__ void split_store(float v, bf16* hi, bf16* lo, size_t idx) {
    bf16 h = __float2bfloat16(v);
    hi[idx] = h;
    lo[idx] = __float2bfloat16(v - __bfloat162float(h));
}

// async global->LDS, 16B per lane. LDS dest is wave-uniform base + lane*16.
__device__ __forceinline__ void gll16(const bf16* g, short* l) {
    __builtin_amdgcn_global_load_lds((const __attribute__((address_space(1))) void*)g,
                                     (__attribute__((address_space(3))) void*)l, 16, 0, 0);
}

// top-2 insert with np.argmin tiebreak (smaller index wins on equal value)
__device__ __forceinline__ void t2_ins(float v, int c, float& v1, int& c1, float& v2, int& c2) {
    const bool b1 = (v < v1) || (v == v1 && c < c1);
    const bool b2 = (v < v2) || (v == v2 && c < c2);
    if (b1) { v2 = v1; c2 = c1; v1 = v; c1 = c; }
    else if (b2) { v2 = v; c2 = c; }
}

// ---------------------------------------------------------------- embed -> y (fp32)
__global__ __launch_bounds__(128) void embed_kernel(const int* __restrict__ tok,
                                                    const float* __restrict__ cb,
                                                    const float* __restrict__ pe,
                                                    float* __restrict__ y) {
    const int row = blockIdx.x;
    const int s = row % SEQ;
    const int t = tok[row];
    const int c = threadIdx.x * 4;
    const float4 cv = *(const float4*)(cb + (size_t)t * E + c);
    const float4 pv = *(const float4*)(pe + (size_t)s * E + c);
    *(float4*)(y + (size_t)row * E + c) =
        make_float4(cv.x + pv.x, cv.y + pv.y, cv.z + pv.z, cv.w + pv.w);
}

// ---------------------------------------------------------------- weight split fp32 -> hi/lo bf16 (compact dst)
__global__ __launch_bounds__(256) void split_w(const float* __restrict__ src, int ld,
                                               int cols_log2, int n,
                                               bf16* __restrict__ hi, bf16* __restrict__ lo) {
    const int i = blockIdx.x * 256 + threadIdx.x;
    if (i >= n) return;
    const int r = i >> cols_log2;
    const int c = i & ((1 << cols_log2) - 1);
    const float v = src[(size_t)r * ld + c];
    split_store(v, hi, lo, i);
}

// ---------------------------------------------------------------- layernorm -> hi/lo planes (1 wave/row)
template<int GELU>
__global__ __launch_bounds__(256) void ln_planes(const float* __restrict__ in,
                                                 bf16* __restrict__ hi, bf16* __restrict__ lo,
                                                 const float* __restrict__ g,
                                                 const float* __restrict__ b) {
    const int lane = threadIdx.x & 63;
    const int row = blockIdx.x * 4 + (threadIdx.x >> 6);
    const float* p = in + (size_t)row * E;
    const float4 v0 = *(const float4*)(p + lane * 4);
    const float4 v1 = *(const float4*)(p + 256 + lane * 4);
    float sum = v0.x + v0.y + v0.z + v0.w + v1.x + v1.y + v1.z + v1.w;
    float sq = v0.x * v0.x + v0.y * v0.y + v0.z * v0.z + v0.w * v0.w
             + v1.x * v1.x + v1.y * v1.y + v1.z * v1.z + v1.w * v1.w;
#pragma unroll
    for (int m = 1; m < 64; m <<= 1) {
        sum += __shfl_xor(sum, m);
        sq += __shfl_xor(sq, m);
    }
    const float mean = sum * (1.0f / 512.0f);
    const float var = sq * (1.0f / 512.0f) - mean * mean;
    const float rstd = rsqrtf(var + 1e-5f);
    const float4 g0 = *(const float4*)(g + lane * 4);
    const float4 g1 = *(const float4*)(g + 256 + lane * 4);
    const float4 b0 = *(const float4*)(b + lane * 4);
    const float4 b1 = *(const float4*)(b + 256 + lane * 4);
    const size_t base = (size_t)row * E;
    float o;
    const float vv0[4] = {v0.x, v0.y, v0.z, v0.w};
    const float gg0[4] = {g0.x, g0.y, g0.z, g0.w};
    const float bb0[4] = {b0.x, b0.y, b0.z, b0.w};
    const float vv1[4] = {v1.x, v1.y, v1.z, v1.w};
    const float gg1[4] = {g1.x, g1.y, g1.z, g1.w};
    const float bb1[4] = {b1.x, b1.y, b1.z, b1.w};
#pragma unroll
    for (int t = 0; t < 4; ++t) {
        o = (vv0[t] - mean) * rstd * gg0[t] + bb0[t];
        if (GELU) o = gelu_f(o);
        split_store(o, hi, lo, base + lane * 4 + t);
        o = (vv1[t] - mean) * rstd * gg1[t] + bb1[t];
        if (GELU) o = gelu_f(o);
        split_store(o, hi, lo, base + 256 + lane * 4 + t);
    }
}

// ---------------------------------------------------------------- split-bf16 MFMA NT GEMM
// C[M,N] = A[M,:]·W[N,:]^T via AhWh + AhWl + AlWh
// 128x128 tile, BK=32, 256 threads = 4 waves (2x2 of 64x64)
// Double-buffered global_load_lds staging with COUNTED vmcnt across raw
// barriers (T4): next tile's 8 DMAs stay in flight across the barrier.
// OUT: 0 = C fp32 (+bias); 1 = C += (+bias); 2 = gelu -> planes;
//      3 = emb(r,c) + resw*(v+bias) -> planes; 4 = plain -> planes;
//      5 = C fp32 AND planes
template<int OUT>
__global__ __launch_bounds__(256) void gemm_split(
    const bf16* __restrict__ Ah, const bf16* __restrict__ Al, int lda,
    const bf16* __restrict__ Wh, const bf16* __restrict__ Wl, int ldw,
    const float* __restrict__ bias,
    float* __restrict__ C, int ldc,
    bf16* __restrict__ Ohi, bf16* __restrict__ Olo, int ldp,
    const int* __restrict__ noisy, const float* __restrict__ cb,
    const float* __restrict__ pe, const float* __restrict__ resw,
    int K) {
    __shared__ __align__(16) short SB[2][4][128][32];   // 64 KB, double-buffered
    const int tid = threadIdx.x;
    const int rowBase = blockIdx.y * 128;
    const int colBase = blockIdx.x * 128;
    const int wave = tid >> 6, lane = tid & 63;
    const int wm = (wave & 1) * 64, wn = (wave >> 1) * 64;
    const int lm = lane & 15;
    const int psl8 = ((lane >> 4) ^ ((lm >> 1) & 3)) * 8;   // swizzled 16B slot for reads

    // staging source for this wave's plane
    const bf16* src = (wave == 0) ? Ah : (wave == 1) ? Al : (wave == 2) ? Wh : Wl;
    const int sld = (wave < 2) ? lda : ldw;
    const int srb = (wave < 2) ? rowBase : colBase;
    const int sslot = (lane & 3) ^ ((lane >> 3) & 3);       // pre-swizzled source slot
    const bf16* sp = src + (size_t)(srb + (lane >> 2)) * sld + sslot * 8;
    short* lb0 = &SB[0][wave][0][0];
    short* lb1 = &SB[1][wave][0][0];

    f32x4 acc[4][4];
#pragma unroll
    for (int i = 0; i < 4; ++i)
#pragma unroll
        for (int j = 0; j < 4; ++j)
            acc[i][j] = (f32x4){0.f, 0.f, 0.f, 0.f};

    const int nt = K >> 5;
    // prologue: stage tiles 0 and 1
#pragma unroll
    for (int j = 0; j < 8; ++j)
        gll16(sp + (size_t)j * 16 * sld, lb0 + j * 512);
    {
        const bf16* p = sp + 32;
#pragma unroll
        for (int j = 0; j < 8; ++j)
            gll16(p + (size_t)j * 16 * sld, lb1 + j * 512);
    }
    for (int t = 0; t < nt; ++t) {
        const int cur = t & 1;
        if (t + 1 < nt) asm volatile("s_waitcnt vmcnt(8)" ::: "memory");
        else            asm volatile("s_waitcnt vmcnt(0)" ::: "memory");
        __builtin_amdgcn_s_barrier();
        __builtin_amdgcn_sched_barrier(0);
        const short (*P)[128][32] = SB[cur];
        short8 ah[4], al[4], wh[4], wl[4];
#pragma unroll
        for (int i = 0; i < 4; ++i) {
            ah[i] = *(const short8*)&P[0][wm + i * 16 + lm][psl8];
            al[i] = *(const short8*)&P[1][wm + i * 16 + lm][psl8];
            wh[i] = *(const short8*)&P[2][wn + i * 16 + lm][psl8];
            wl[i] = *(const short8*)&P[3][wn + i * 16 + lm][psl8];
        }
#pragma unroll
        for (int i = 0; i < 4; ++i)
#pragma unroll
            for (int j = 0; j < 4; ++j)
                acc[i][j] = __builtin_amdgcn_mfma_f32_16x16x32_bf16(ah[i], wh[j], acc[i][j], 0, 0, 0);
#pragma unroll
        for (int i = 0; i < 4; ++i)
#pragma unroll
            for (int j = 0; j < 4; ++j)
                acc[i][j] = __builtin_amdgcn_mfma_f32_16x16x32_bf16(ah[i], wl[j], acc[i][j], 0, 0, 0);
#pragma unroll
        for (int i = 0; i < 4; ++i)
#pragma unroll
            for (int j = 0; j < 4; ++j)
                acc[i][j] = __builtin_amdgcn_mfma_f32_16x16x32_bf16(al[i], wh[j], acc[i][j], 0, 0, 0);
        __builtin_amdgcn_s_barrier();      // all waves done reading SB[cur]
        if (t + 2 < nt) {                  // refill SB[cur] with tile t+2
            short* lb = cur ? lb1 : lb0;
            const bf16* p = sp + (t + 2) * 32;
#pragma unroll
            for (int j = 0; j < 8; ++j)
                gll16(p + (size_t)j * 16 * sld, lb + j * 512);
        }
    }

    // epilogue: C/D layout col = lane&15, row = (lane>>4)*4 + reg
    float bv[4];
#pragma unroll
    for (int j = 0; j < 4; ++j)
        bv[j] = bias ? bias[colBase + wn + j * 16 + lm] : 0.f;
    float scv = 0.f;
    if (OUT == 3) scv = resw[0];
#pragma unroll
    for (int i = 0; i < 4; ++i) {
#pragma unroll
        for (int reg = 0; reg < 4; ++reg) {
            const int r = rowBase + wm + i * 16 + (lane >> 4) * 4 + reg;
            int tok = 0, srow = 0;
            if (OUT == 3) { tok = noisy[r]; srow = r % SEQ; }
#pragma unroll
            for (int j = 0; j < 4; ++j) {
                const int col = colBase + wn + j * 16 + lm;
                float v = acc[i][j][reg] + bv[j];
                if (OUT == 0) {
                    C[(size_t)r * ldc + col] = v;
                } else if (OUT == 1) {
                    float* cp = C + (size_t)r * ldc + col;
                    *cp = *cp + v;
                } else if (OUT == 2) {
                    v = gelu_f(v);
                    split_store(v, Ohi, Olo, (size_t)r * ldp + col);
                } else if (OUT == 3) {
                    const float xv = cb[(size_t)tok * E + col] + pe[(size_t)srow * E + col];
                    v = xv + scv * v;
                    split_store(v, Ohi, Olo, (size_t)r * ldp + col);
                } else if (OUT == 4) {
                    split_store(v, Ohi, Olo, (size_t)r * ldp + col);
                } else { // OUT == 5
                    C[(size_t)r * ldc + col] = v;
                    split_store(v, Ohi, Olo, (size_t)r * ldp + col);
                }
            }
        }
    }
}

// ---------------------------------------------------------------- V transpose: qkv planes -> Vt[bh*64+d][s] (ld VLD)
__global__ __launch_bounds__(256) void vtrans(const bf16* __restrict__ vh_src,
                                              const bf16* __restrict__ vl_src,
                                              bf16* __restrict__ vth,
                                              bf16* __restrict__ vtl) {
    __shared__ short T[64][72];
    const int tid = threadIdx.x;
    const int st = blockIdx.x;   // 16 s-tiles of 64
    const int bh = blockIdx.y;   // 128
    const int b = bh >> 3, h = bh & 7;
    const int sr = tid >> 2, dq = (tid & 3) * 16;
    const int s_g = st * 64 + sr;
    const int od = tid >> 3;          // 0..31 (+32)
    const int osq = (tid & 7) * 8;    // 0..56
#pragma unroll
    for (int p = 0; p < 2; ++p) {
        const short* src = (const short*)(p ? vl_src : vh_src);
        short* dst = (short*)(p ? vtl : vth);
        short8 a0 = {0, 0, 0, 0, 0, 0, 0, 0};
        short8 a1 = {0, 0, 0, 0, 0, 0, 0, 0};
        if (s_g < SEQ) {
            const short* sp = src + (size_t)(b * SEQ + s_g) * 1536 + 1024 + h * 64 + dq;
            a0 = *(const short8*)sp;
            a1 = *(const short8*)(sp + 8);
        }
        __syncthreads();
#pragma unroll
        for (int j = 0; j < 8; ++j) T[dq + j][sr] = a0[j];
#pragma unroll
        for (int j = 0; j < 8; ++j) T[dq + 8 + j][sr] = a1[j];
        __syncthreads();
        const int scol = st * 64 + osq;
        if (scol + 8 <= VLD) {
            const short8 o0 = *(const short8*)&T[od][osq];
            const short8 o1 = *(const short8*)&T[od + 32][osq];
            *(short8*)(dst + (size_t)(bh * 64 + od) * VLD + scol) = o0;
            *(short8*)(dst + (size_t)(bh * 64 + od + 32) * VLD + scol) = o1;
        }
    }
}

// ---------------------------------------------------------------- MFMA flash attention (split bf16)
__global__ __launch_bounds__(256) void attn_mfma(const bf16* __restrict__ qkh,
                                                 const bf16* __restrict__ qkl,
                                                 const bf16* __restrict__ vth,
                                                 const bf16* __restrict__ vtl,
                                                 bf16* __restrict__ chi,
                                                 bf16* __restrict__ clo) {
    __shared__ short QPs[2][64][72];   // Q staging, then P
    __shared__ short Ks[2][64][72];
    __shared__ short Vs[2][64][72];    // Vt tile: [d][n]
    const int tid = threadIdx.x;
    const int qt = blockIdx.x, bh = blockIdx.y;
    const int b = bh >> 3, h = bh & 7;
    const int wave = tid >> 6, lane = tid & 63;
    const int lm = lane & 15, g = lane >> 4, q8 = g * 8;
    const int wq = wave * 16;
    const int r0 = tid >> 2, kq = (tid & 3) * 16;
    const short8 z = {0, 0, 0, 0, 0, 0, 0, 0};

    {
        const int q = qt * 64 + r0;
        short8 a0 = z, a1 = z, b0 = z, b1 = z;
        if (q < SEQ) {
            const size_t base = (size_t)(b * SEQ + q) * 1536 + h * 64 + kq;
            a0 = *(const short8*)((const short*)qkh + base);
            a1 = *(const short8*)((const short*)qkh + base + 8);
            b0 = *(const short8*)((const short*)qkl + base);
            b1 = *(const short8*)((const short*)qkl + base + 8);
        }
        *(short8*)&QPs[0][r0][kq] = a0; *(short8*)&QPs[0][r0][kq + 8] = a1;
        *(short8*)&QPs[1][r0][kq] = b0; *(short8*)&QPs[1][r0][kq + 8] = b1;
    }
    __syncthreads();
    short8 qfh[2], qfl[2];
#pragma unroll
    for (int t = 0; t < 2; ++t) {
        qfh[t] = *(const short8*)&QPs[0][wq + lm][t * 32 + q8];
        qfl[t] = *(const short8*)&QPs[1][wq + lm][t * 32 + q8];
    }

    float m_i[4] = {-3e38f, -3e38f, -3e38f, -3e38f};
    float l_i[4] = {0.f, 0.f, 0.f, 0.f};
    f32x4 o[4];
#pragma unroll
    for (int dt = 0; dt < 4; ++dt) o[dt] = (f32x4){0.f, 0.f, 0.f, 0.f};

    // K/V staging registers (prefetched one tile ahead)
    short8 ka0 = z, ka1 = z, kl0 = z, kl1 = z;
    short8 va0 = z, va1 = z, vl0 = z, vl1 = z;
    auto loadKV = [&](int kb2) {
        const int kr = kb2 + r0;
        ka0 = z; ka1 = z; kl0 = z; kl1 = z;
        if (kr < SEQ) {
            const size_t base = (size_t)(b * SEQ + kr) * 1536 + 512 + h * 64 + kq;
            ka0 = *(const short8*)((const short*)qkh + base);
            ka1 = *(const short8*)((const short*)qkh + base + 8);
            kl0 = *(const short8*)((const short*)qkl + base);
            kl1 = *(const short8*)((const short*)qkl + base + 8);
        }
        const size_t vbase = (size_t)(bh * 64 + r0) * VLD + kb2 + kq;
        va0 = z; va1 = z; vl0 = z; vl1 = z;
        if (kb2 + kq + 8 <= VLD) {
            va0 = *(const short8*)((const short*)vth + vbase);
            vl0 = *(const short8*)((const short*)vtl + vbase);
        }
        if (kb2 + kq + 16 <= VLD) {
            va1 = *(const short8*)((const short*)vth + vbase + 8);
            vl1 = *(const short8*)((const short*)vtl + vbase + 8);
        }
    };
    loadKV(0);

    for (int kb = 0; kb < SEQ; kb += 64) {
        __syncthreads();
        {
            *(short8*)&Ks[0][r0][kq] = ka0; *(short8*)&Ks[0][r0][kq + 8] = ka1;
            *(short8*)&Ks[1][r0][kq] = kl0; *(short8*)&Ks[1][r0][kq + 8] = kl1;
            *(short8*)&Vs[0][r0][kq] = va0; *(short8*)&Vs[0][r0][kq + 8] = va1;
            *(short8*)&Vs[1][r0][kq] = vl0; *(short8*)&Vs[1][r0][kq + 8] = vl1;
        }
        __syncthreads();
        if (kb + 64 < SEQ) loadKV(kb + 64);   // prefetch: overlaps QK^T + softmax
        f32x4 sac[4];
#pragma unroll
        for (int j = 0; j < 4; ++j) sac[j] = (f32x4){0.f, 0.f, 0.f, 0.f};
#pragma unroll
        for (int t = 0; t < 2; ++t) {
#pragma unroll
            for (int j = 0; j < 4; ++j) {
                const short8 kh = *(const short8*)&Ks[0][j * 16 + lm][t * 32 + q8];
                const short8 kl = *(const short8*)&Ks[1][j * 16 + lm][t * 32 + q8];
                sac[j] = __builtin_amdgcn_mfma_f32_16x16x32_bf16(qfh[t], kh, sac[j], 0, 0, 0);
                sac[j] = __builtin_amdgcn_mfma_f32_16x16x32_bf16(qfh[t], kl, sac[j], 0, 0, 0);
                sac[j] = __builtin_amdgcn_mfma_f32_16x16x32_bf16(qfl[t], kh, sac[j], 0, 0, 0);
            }
        }
        float alpha_v[4];
#pragma unroll
        for (int reg = 0; reg < 4; ++reg) {
            float sv[4];
            float rm = -3e38f;
#pragma unroll
            for (int j = 0; j < 4; ++j) {
                const int kc = kb + j * 16 + lm;
                float s = sac[j][reg] * 0.125f;
                s = (kc < SEQ) ? s : -3e38f;
                sv[j] = s;
                rm = fmaxf(rm, s);
            }
#pragma unroll
            for (int m = 1; m < 16; m <<= 1) rm = fmaxf(rm, __shfl_xor(rm, m));
            const float mn = fmaxf(m_i[reg], rm);
            const float al = expf(m_i[reg] - mn);
            float rs = 0.f;
            const int prow = wq + g * 4 + reg;
#pragma unroll
            for (int j = 0; j < 4; ++j) {
                const float pv = expf(sv[j] - mn);
                rs += pv;
                bf16 phb = __float2bfloat16(pv);
                bf16 plb = __float2bfloat16(pv - __bfloat162float(phb));
                QPs[0][prow][j * 16 + lm] = *reinterpret_cast<short*>(&phb);
                QPs[1][prow][j * 16 + lm] = *reinterpret_cast<short*>(&plb);
            }
#pragma unroll
            for (int m = 1; m < 16; m <<= 1) rs += __shfl_xor(rs, m);
            l_i[reg] = l_i[reg] * al + rs;
            m_i[reg] = mn;
            alpha_v[reg] = al;
        }
        const f32x4 av = {alpha_v[0], alpha_v[1], alpha_v[2], alpha_v[3]};
#pragma unroll
        for (int dt = 0; dt < 4; ++dt) o[dt] *= av;
        __syncthreads();
#pragma unroll
        for (int t = 0; t < 2; ++t) {
            const short8 ph = *(const short8*)&QPs[0][wq + lm][t * 32 + q8];
            const short8 pl = *(const short8*)&QPs[1][wq + lm][t * 32 + q8];
#pragma unroll
            for (int dt = 0; dt < 4; ++dt) {
                const short8 vh = *(const short8*)&Vs[0][dt * 16 + lm][t * 32 + q8];
                const short8 vl = *(const short8*)&Vs[1][dt * 16 + lm][t * 32 + q8];
                o[dt] = __builtin_amdgcn_mfma_f32_16x16x32_bf16(ph, vh, o[dt], 0, 0, 0);
                o[dt] = __builtin_amdgcn_mfma_f32_16x16x32_bf16(ph, vl, o[dt], 0, 0, 0);
                o[dt] = __builtin_amdgcn_mfma_f32_16x16x32_bf16(pl, vh, o[dt], 0, 0, 0);
            }
        }
    }
#pragma unroll
    for (int reg = 0; reg < 4; ++reg) {
        const int q = qt * 64 + wq + g * 4 + reg;
        if (q < SEQ) {
            const float inv = 1.0f / l_i[reg];
#pragma unroll
            for (int dt = 0; dt < 4; ++dt) {
                const size_t idx = (size_t)(b * SEQ + q) * E + h * 64 + dt * 16 + lm;
                split_store(o[dt][reg] * inv, chi, clo, idx);
            }
        }
    }
}

// ---------------------------------------------------------------- codebook row norms
__global__ __launch_bounds__(256) void cbnorm_kernel(const float* __restrict__ cb,
                                                     float* __restrict__ out) {
    const int lane = threadIdx.x & 63;
    const int row = blockIdx.x * 4 + (threadIdx.x >> 6);
    const float* p = cb + (size_t)row * E;
    const float4 v0 = *(const float4*)(p + lane * 4);
    const float4 v1 = *(const float4*)(p + 256 + lane * 4);
    float sq = v0.x * v0.x + v0.y * v0.y + v0.z * v0.z + v0.w * v0.w
             + v1.x * v1.x + v1.y * v1.y + v1.z * v1.z + v1.w * v1.w;
#pragma unroll
    for (int m = 1; m < 64; m <<= 1) sq += __shfl_xor(sq, m);
    if (lane == 0) out[row] = sq;
}

// ---------------------------------------------------------------- stage A: split-bf16 MFMA distance, A-in-registers
// 250 blocks x 256 threads (4 waves); wave owns 16 fc rows; lane holds all A
// frags in regs (a_h[16], a_l[16]). W (cb planes) streams through a 32KB LDS
// double buffer with counted vmcnt (proven T4 schedule). All blocks sweep W
// in lockstep -> per-XCD L2 sharing; A fetched exactly once.
// Per-lane running top2 (cols == lm mod 16), shuffle-merged across 16 lanes.
// part[row] = (v1, idx1, v2, idx2)
__global__ __launch_bounds__(256, 1) void argmin_mfma(
    const bf16* __restrict__ Ah, const bf16* __restrict__ Al,
    const bf16* __restrict__ Wh, const bf16* __restrict__ Wl,
    const float* __restrict__ cbn, float4* __restrict__ part) {
    __shared__ __align__(16) short Wreg[2][8192];   // 32 KB: [buf][(plane*128+col)*32]
    const int tid = threadIdx.x;
    const int rowBase = blockIdx.x * 64;
    const int wave = tid >> 6, lane = tid & 63;
    const int lm = lane & 15, g = lane >> 4;
    const int g8 = g * 8;
    const int psl8 = (g ^ ((lm >> 1) & 3)) * 8;
    const int sslot = (lane & 3) ^ ((lane >> 3) & 3);
    const int srow = lane >> 2;
    const int row = rowBase + wave * 16 + lm;   // the A row this lane's frags cover

    // ---- A -> registers (once): 16 k-chunks x 2 planes, 16B frag each.
    // Lanes {lm, lm+16, lm+32, lm+48} read 64B contiguous per row per chunk.
    short8 a_h[16], a_l[16];
#pragma unroll
    for (int c = 0; c < 16; ++c) {
        a_h[c] = *(const short8*)(Ah + (size_t)row * E + c * 32 + g8);
        a_l[c] = *(const short8*)(Al + (size_t)row * E + c * 32 + g8);
    }

    // ---- W staging: tile s (ct = s>>4 col-tile, k = s&15) -> buf s&1.
    // 16 pieces of 1KB; wave stages 4 -> 4 gll16/wave/step.
    auto stageW = [&](int s) {
        const int ct = s >> 4, k = s & 15;
        const int colB = ct * 128;
        short* dstb = &Wreg[s & 1][0];
#pragma unroll
        for (int e = 0; e < 4; ++e) {
            const int m = wave * 4 + e;   // 0..15
            const int p = m >> 3;         // plane
            const int j = m & 7;          // 16-col group
            const bf16* srcp = p ? Wl : Wh;
            gll16(srcp + (size_t)(colB + j * 16 + srow) * E + k * 32 + sslot * 8,
                  dstb + ((p * 128 + j * 16) * 32));
        }
    };
    stageW(0);
    stageW(1);

    float rv1[4], rv2[4];
    int rc1[4], rc2[4];
#pragma unroll
    for (int r = 0; r < 4; ++r) {
        rv1[r] = 3e38f; rv2[r] = 3e38f;
        rc1[r] = 0x7fffffff; rc2[r] = 0x7fffffff;
    }
    f32x4 acc[8];
#pragma unroll
    for (int j = 0; j < 8; ++j) acc[j] = (f32x4){0.f, 0.f, 0.f, 0.f};

    for (int ct = 0; ct < 32; ++ct) {
        const int colB = ct * 128;
#pragma unroll
        for (int k = 0; k < 16; ++k) {      // full unroll: a_h[k]/a_l[k] static (rule #20)
            const int s = ct * 16 + k;
            if (s + 1 < 512) asm volatile("s_waitcnt vmcnt(4)" ::: "memory");
            else             asm volatile("s_waitcnt vmcnt(0)" ::: "memory");
            __builtin_amdgcn_s_barrier();
            __builtin_amdgcn_sched_barrier(0);
            const short* B = &Wreg[s & 1][0];
#pragma unroll
            for (int j = 0; j < 8; ++j) {
                const short8 wh = *(const short8*)(B + (j * 16 + lm) * 32 + psl8);
                const short8 wl = *(const short8*)(B + (128 + j * 16 + lm) * 32 + psl8);
                acc[j] = __builtin_amdgcn_mfma_f32_16x16x32_bf16(a_h[k], wh, acc[j], 0, 0, 0);
                acc[j] = __builtin_amdgcn_mfma_f32_16x16x32_bf16(a_h[k], wl, acc[j], 0, 0, 0);
                acc[j] = __builtin_amdgcn_mfma_f32_16x16x32_bf16(a_l[k], wh, acc[j], 0, 0, 0);
            }
            __builtin_amdgcn_s_barrier();     // all waves done reading Wreg[s&1]
            if (s + 2 < 512) stageW(s + 2);   // refill Wreg[s&1] with tile s+2
        }
        // ct finished: fold 128 cols into per-lane running top2
#pragma unroll
        for (int j = 0; j < 8; ++j) {
            const int col = colB + j * 16 + lm;
            const float nv = cbn[col];
#pragma unroll
            for (int r = 0; r < 4; ++r) {
                const float d = nv - 2.0f * acc[j][r];
                t2_ins(d, col, rv1[r], rc1[r], rv2[r], rc2[r]);
            }
            acc[j] = (f32x4){0.f, 0.f, 0.f, 0.f};
        }
    }

    // ---- merge across the 16 lm lanes of each g group; lm==0 writes its rows
#pragma unroll
    for (int r = 0; r < 4; ++r) {
#pragma unroll
        for (int m = 1; m < 16; m <<= 1) {
            const float w1 = __shfl_xor(rv1[r], m); const int d1 = __shfl_xor(rc1[r], m);
            const float w2 = __shfl_xor(rv2[r], m); const int d2 = __shfl_xor(rc2[r], m);
            t2_ins(w1, d1, rv1[r], rc1[r], rv2[r], rc2[r]);
            t2_ins(w2, d2, rv1[r], rc1[r], rv2[r], rc2[r]);
        }
    }
    if (lm == 0) {
#pragma unroll
        for (int r = 0; r < 4; ++r)
            part[rowBase + wave * 16 + g * 4 + r] =
                make_float4(rv1[r], (float)rc1[r], rv2[r], (float)rc2[r]);
    }
}

// ---------------------------------------------------------------- stage B: exact fp32 rescore of top2
__global__ __launch_bounds__(256) void argmin_exact(const float4* __restrict__ part,
                                                    const float* __restrict__ fc,
                                                    const float* __restrict__ cb,
                                                    const float* __restrict__ cbn,
                                                    float* __restrict__ tokf) {
    const int wave = threadIdx.x >> 6, lane = threadIdx.x & 63;
    const int r = blockIdx.x * 4 + wave;   // 4000 blocks
    const float4 p = part[r];
    const int c1 = (int)p.y;
    const int c2 = (int)p.w;
    // exact fp32 d2 for c1, c2
    const float* fr = fc + (size_t)r * E + lane * 8;
    const float* p1 = cb + (size_t)c1 * E + lane * 8;
    const float* p2 = cb + (size_t)c2 * E + lane * 8;
    float d1 = 0.f, d2 = 0.f;
#pragma unroll
    for (int j = 0; j < 8; ++j) {
        const float f = fr[j];
        d1 += f * p1[j];
        d2 += f * p2[j];
    }
#pragma unroll
    for (int m = 1; m < 64; m <<= 1) {
        d1 += __shfl_xor(d1, m);
        d2 += __shfl_xor(d2, m);
    }
    d1 = cbn[c1] - 2.0f * d1;
    d2 = cbn[c2] - 2.0f * d2;
    const int win = ((d1 < d2) || (d1 == d2 && c1 < c2)) ? c1 : c2;
    if (lane == 0) tokf[r] = (float)win;
}

// ---------------------------------------------------------------- launch
extern "C" void kernel_launch(void* const* d_in, const int* in_sizes, int n_in,
                              void* d_out, int out_size, void* d_ws, size_t ws_size,
                              hipStream_t stream) {
    const int* noisy = (const int*)d_in[0];
    const float* codebook = (const float*)d_in[1];
    const float* pos_enc = (const float*)d_in[2];
    const float* qkv_w = (const float*)d_in[3];
    const float* qkv_b = (const float*)d_in[4];
    const float* out_w = (const float*)d_in[5];
    const float* out_b = (const float*)d_in[6];
    const float* ln1_g = (const float*)d_in[7];
    const float* ln1_b = (const float*)d_in[8];
    const float* ln2_g = (const float*)d_in[9];
    const float* ln2_b = (const float*)d_in[10];
    const float* ff1_w = (const float*)d_in[11];
    const float* ff1_b = (const float*)d_in[12];
    const float* ff2_w = (const float*)d_in[13];
    const float* ff2_b = (const float*)d_in[14];
    const float* fin_g = (const float*)d_in[15];
    const float* fin_b = (const float*)d_in[16];
    const float* pp1_w = (const float*)d_in[17];
    const float* pp1_b = (const float*)d_in[18];
    const float* pp_ln_g = (const float*)d_in[19];
    const float* pp_ln_b = (const float*)d_in[20];
    const float* pp2_w = (const float*)d_in[21];
    const float* pp2_b = (const float*)d_in[22];
    const float* res_w = (const float*)d_in[23];
    const float* fc1_w = (const float*)d_in[24];
    const float* fc1_b = (const float*)d_in[25];
    const float* fc_ln_g = (const float*)d_in[26];
    const float* fc_ln_b = (const float*)d_in[27];
    const float* fc2_w = (const float*)d_in[28];
    const float* fc2_b = (const float*)d_in[29];

    // workspace (floats), total 41,025,536 floats = 164.1 MB
    float* ws = (float*)d_ws;
    float* y = ws;                        // [0, 8.192M)
    float* REG = ws + 8192000;            // [8.192M, 32.768M)
    bf16* qkvh = (bf16*)REG;              // 16000x1536 shorts
    bf16* qkvl = qkvh + 24576000;
    bf16* mid_hi = (bf16*)REG;            // FF phase: 16000x1024
    bf16* mid_lo = mid_hi + 16384000;
    float* slotA = REG;                   // tail: e planes / fc fp32
    float* slotB = REG + 8192000;         // tail: pp1/fc1 fp32 tmp, then cbn+partials
    bf16* e_hi = (bf16*)slotA;
    bf16* e_lo = e_hi + 8192000;
    bf16* fcp2_hi = (bf16*)(REG + 16384000);  // fc planes (spare tail region)
    bf16* fcp2_lo = fcp2_hi + 8192000;
    float* WV = ws + 32768000;            // [32.768M, 41.0255M): Vt planes OR weight splits OR cb planes
    bf16* vth = (bf16*)WV;                // 8192 x VLD
    bf16* vtl = vth + 8192 * VLD;
    bf16* wA_hi = (bf16*)WV;              // cap 2048x512 each
    bf16* wA_lo = wA_hi + 1048576;
    bf16* wB_hi = wA_lo + 1048576;
    bf16* wB_lo = wB_hi + 1048576;
    bf16* cbh = wB_lo + 1048576;          // 4096x512, after weights (tail only)
    bf16* cbl = cbh + 2097152;
    float* cbn = slotB;                   // tail-only
    float4* part = (float4*)(slotB + 4096);  // 16000 float4
    // h planes live in d_out (dead before final outputs are written)
    bf16* h_hi = (bf16*)d_out;
    bf16* h_lo = h_hi + 8192000;
    float* tokf = (float*)d_out + 8192000;

    const dim3 blk(256);
    const dim3 g512(4, 125), g1024(8, 125), g1536(12, 125);

    embed_kernel<<<dim3(NTOK), dim3(128), 0, stream>>>(noisy, codebook, pos_enc, y);

    for (int l = 0; l < 4; ++l) {
        ln_planes<0><<<dim3(4000), blk, 0, stream>>>(y, h_hi, h_lo, ln1_g + l * E, ln1_b + l * E);
        split_w<<<dim3(3072), blk, 0, stream>>>(qkv_w + (size_t)l * 1536 * E, E, 9, 1536 * E, wA_hi, wA_lo);
        gemm_split<4><<<g1536, blk, 0, stream>>>(
            h_hi, h_lo, E, wA_hi, wA_lo, E, qkv_b + (size_t)l * 1536,
            nullptr, 0, qkvh, qkvl, 1536, nullptr, nullptr, nullptr, nullptr, E);
        vtrans<<<dim3(16, 128), blk, 0, stream>>>(qkvh, qkvl, vth, vtl);  // overwrites wA (dead)
        attn_mfma<<<dim3(16, 128), blk, 0, stream>>>(qkvh, qkvl, vth, vtl, h_hi, h_lo);
        split_w<<<dim3(1024), blk, 0, stream>>>(out_w + (size_t)l * E * E, E, 9, E * E, wB_hi, wB_lo);
        gemm_split<1><<<g512, blk, 0, stream>>>(
            h_hi, h_lo, E, wB_hi, wB_lo, E, out_b + (size_t)l * E,
            y, E, nullptr, nullptr, 0, nullptr, nullptr, nullptr, nullptr, E);
        ln_planes<0><<<dim3(4000), blk, 0, stream>>>(y, h_hi, h_lo, ln2_g + l * E, ln2_b + l * E);
        split_w<<<dim3(4096), blk, 0, stream>>>(ff1_w + (size_t)l * FFD * E, E, 9, FFD * E, wA_hi, wA_lo);
        split_w<<<dim3(4096), blk, 0, stream>>>(ff2_w + (size_t)l * E * FFD, FFD, 11, E * FFD, wB_hi, wB_lo);
        for (int c = 0; c < 2; ++c) {
            gemm_split<2><<<g1024, blk, 0, stream>>>(
                h_hi, h_lo, E, wA_hi + (size_t)c * 1024 * E, wA_lo + (size_t)c * 1024 * E, E,
                ff1_b + (size_t)l * FFD + c * 1024,
                nullptr, 0, mid_hi, mid_lo, 1024, nullptr, nullptr, nullptr, nullptr, E);
            gemm_split<1><<<g512, blk, 0, stream>>>(
                mid_hi, mid_lo, 1024, wB_hi + c * 1024, wB_lo + c * 1024, FFD,
                (c == 0) ? (ff2_b + (size_t)l * E) : nullptr,
                y, E, nullptr, nullptr, 0, nullptr, nullptr, nullptr, nullptr, 1024);
        }
    }

    // tail
    ln_planes<0><<<dim3(4000), blk, 0, stream>>>(y, h_hi, h_lo, fin_g, fin_b);
    split_w<<<dim3(1024), blk, 0, stream>>>(pp1_w, E, 9, E * E, wA_hi, wA_lo);
    gemm_split<0><<<g512, blk, 0, stream>>>(
        h_hi, h_lo, E, wA_hi, wA_lo, E, pp1_b,
        slotB, E, nullptr, nullptr, 0, nullptr, nullptr, nullptr, nullptr, E);
    ln_planes<1><<<dim3(4000), blk, 0, stream>>>(slotB, h_hi, h_lo, pp_ln_g, pp_ln_b);
    split_w<<<dim3(1024), blk, 0, stream>>>(pp2_w, E, 9, E * E, wB_hi, wB_lo);
    gemm_split<3><<<g512, blk, 0, stream>>>(
        h_hi, h_lo, E, wB_hi, wB_lo, E, pp2_b,
        nullptr, 0, e_hi, e_lo, E, noisy, codebook, pos_enc, res_w, E);
    split_w<<<dim3(1024), blk, 0, stream>>>(fc1_w, E, 9, E * E, wA_hi, wA_lo);
    gemm_split<0><<<g512, blk, 0, stream>>>(
        e_hi, e_lo, E, wA_hi, wA_lo, E, fc1_b,
        slotB, E, nullptr, nullptr, 0, nullptr, nullptr, nullptr, nullptr, E);
    ln_planes<1><<<dim3(4000), blk, 0, stream>>>(slotB, h_hi, h_lo, fc_ln_g, fc_ln_b);
    split_w<<<dim3(1024), blk, 0, stream>>>(fc2_w, E, 9, E * E, wB_hi, wB_lo);
    gemm_split<5><<<g512, blk, 0, stream>>>(
        h_hi, h_lo, E, wB_hi, wB_lo, E, fc2_b,
        slotA, E, fcp2_hi, fcp2_lo, E, nullptr, nullptr, nullptr, nullptr, E);  // fc fp32 + planes

    // argmin: A-in-registers MFMA top2 + exact fp32 rescore
    split_w<<<dim3(8192), blk, 0, stream>>>(codebook, E, 9, CBN * E, cbh, cbl);
    cbnorm_kernel<<<dim3(1024), blk, 0, stream>>>(codebook, cbn);
    argmin_mfma<<<dim3(250), blk, 0, stream>>>(fcp2_hi, fcp2_lo, cbh, cbl, cbn, part);
    argmin_exact<<<dim3(4000), blk, 0, stream>>>(part, slotA, codebook, cbn, tokf);
    hipMemcpyAsync(d_out, slotA, (size_t)8192000 * 4, hipMemcpyDeviceToDevice, stream);
}

// Round 6
// 3548.671 us; speedup vs baseline: 1.0323x; 1.0323x over previous
//
#include <hip/hip_runtime.h>
#include <hip/hip_bf16.h>
#include <math.h>

#define NTOK 16000
#define E    512
#define FFD  2048
#define CBN  4096
#define SEQ  1000
#define NH   8
#define VLD  1008   // Vt padded leading dim (s), multiple of 8

typedef __hip_bfloat16 bf16;
typedef __attribute__((ext_vector_type(8))) short short8;
typedef __attribute__((ext_vector_type(4))) float f32x4;

__device__ __forceinline__ float gelu_f(float v) {
    return 0.5f * v * (1.0f + erff(v * 0.70710678118654752f));
}

__device__ __forceinline__ void split_store(float v, bf16* hi, bf16* lo, size_t idx) {
    bf16 h = __float2bfloat16(v);
    hi[idx] = h;
    lo[idx] = __float2bfloat16(v - __bfloat162float(h));
}

// async global->LDS, 16B per lane. LDS dest is wave-uniform base + lane*16.
__device__ __forceinline__ void gll16(const bf16* g, short* l) {
    __builtin_amdgcn_global_load_lds((const __attribute__((address_space(1))) void*)g,
                                     (__attribute__((address_space(3))) void*)l, 16, 0, 0);
}

// top-2 insert with np.argmin tiebreak (smaller index wins on equal value)
__device__ __forceinline__ void t2_ins(float v, int c, float& v1, int& c1, float& v2, int& c2) {
    const bool b1 = (v < v1) || (v == v1 && c < c1);
    const bool b2 = (v < v2) || (v == v2 && c < c2);
    if (b1) { v2 = v1; c2 = c1; v1 = v; c1 = c; }
    else if (b2) { v2 = v; c2 = c; }
}

// ---------------------------------------------------------------- embed -> y (fp32)
__global__ __launch_bounds__(128) void embed_kernel(const int* __restrict__ tok,
                                                    const float* __restrict__ cb,
                                                    const float* __restrict__ pe,
                                                    float* __restrict__ y) {
    const int row = blockIdx.x;
    const int s = row % SEQ;
    const int t = tok[row];
    const int c = threadIdx.x * 4;
    const float4 cv = *(const float4*)(cb + (size_t)t * E + c);
    const float4 pv = *(const float4*)(pe + (size_t)s * E + c);
    *(float4*)(y + (size_t)row * E + c) =
        make_float4(cv.x + pv.x, cv.y + pv.y, cv.z + pv.z, cv.w + pv.w);
}

// ---------------------------------------------------------------- weight split fp32 -> hi/lo bf16 (compact dst)
__global__ __launch_bounds__(256) void split_w(const float* __restrict__ src, int ld,
                                               int cols_log2, int n,
                                               bf16* __restrict__ hi, bf16* __restrict__ lo) {
    const int i = blockIdx.x * 256 + threadIdx.x;
    if (i >= n) return;
    const int r = i >> cols_log2;
    const int c = i & ((1 << cols_log2) - 1);
    const float v = src[(size_t)r * ld + c];
    split_store(v, hi, lo, i);
}

// ---------------------------------------------------------------- layernorm -> hi/lo planes (1 wave/row)
template<int GELU>
__global__ __launch_bounds__(256) void ln_planes(const float* __restrict__ in,
                                                 bf16* __restrict__ hi, bf16* __restrict__ lo,
                                                 const float* __restrict__ g,
                                                 const float* __restrict__ b) {
    const int lane = threadIdx.x & 63;
    const int row = blockIdx.x * 4 + (threadIdx.x >> 6);
    const float* p = in + (size_t)row * E;
    const float4 v0 = *(const float4*)(p + lane * 4);
    const float4 v1 = *(const float4*)(p + 256 + lane * 4);
    float sum = v0.x + v0.y + v0.z + v0.w + v1.x + v1.y + v1.z + v1.w;
    float sq = v0.x * v0.x + v0.y * v0.y + v0.z * v0.z + v0.w * v0.w
             + v1.x * v1.x + v1.y * v1.y + v1.z * v1.z + v1.w * v1.w;
#pragma unroll
    for (int m = 1; m < 64; m <<= 1) {
        sum += __shfl_xor(sum, m);
        sq += __shfl_xor(sq, m);
    }
    const float mean = sum * (1.0f / 512.0f);
    const float var = sq * (1.0f / 512.0f) - mean * mean;
    const float rstd = rsqrtf(var + 1e-5f);
    const float4 g0 = *(const float4*)(g + lane * 4);
    const float4 g1 = *(const float4*)(g + 256 + lane * 4);
    const float4 b0 = *(const float4*)(b + lane * 4);
    const float4 b1 = *(const float4*)(b + 256 + lane * 4);
    const size_t base = (size_t)row * E;
    float o;
    const float vv0[4] = {v0.x, v0.y, v0.z, v0.w};
    const float gg0[4] = {g0.x, g0.y, g0.z, g0.w};
    const float bb0[4] = {b0.x, b0.y, b0.z, b0.w};
    const float vv1[4] = {v1.x, v1.y, v1.z, v1.w};
    const float gg1[4] = {g1.x, g1.y, g1.z, g1.w};
    const float bb1[4] = {b1.x, b1.y, b1.z, b1.w};
#pragma unroll
    for (int t = 0; t < 4; ++t) {
        o = (vv0[t] - mean) * rstd * gg0[t] + bb0[t];
        if (GELU) o = gelu_f(o);
        split_store(o, hi, lo, base + lane * 4 + t);
        o = (vv1[t] - mean) * rstd * gg1[t] + bb1[t];
        if (GELU) o = gelu_f(o);
        split_store(o, hi, lo, base + 256 + lane * 4 + t);
    }
}

// ---------------------------------------------------------------- split-bf16 MFMA NT GEMM
// C[M,N] = A[M,:]·W[N,:]^T via AhWh + AhWl + AlWh
// 128x128 tile, BK=32, 256 threads = 4 waves (2x2 of 64x64)
// Double-buffered global_load_lds staging with COUNTED vmcnt across raw
// barriers (T4): next tile's 8 DMAs stay in flight across the barrier.
// OUT: 0 = C fp32 (+bias); 1 = C += (+bias); 2 = gelu -> planes;
//      3 = emb(r,c) + resw*(v+bias) -> planes; 4 = plain -> planes;
//      5 = C fp32 AND planes
template<int OUT>
__global__ __launch_bounds__(256) void gemm_split(
    const bf16* __restrict__ Ah, const bf16* __restrict__ Al, int lda,
    const bf16* __restrict__ Wh, const bf16* __restrict__ Wl, int ldw,
    const float* __restrict__ bias,
    float* __restrict__ C, int ldc,
    bf16* __restrict__ Ohi, bf16* __restrict__ Olo, int ldp,
    const int* __restrict__ noisy, const float* __restrict__ cb,
    const float* __restrict__ pe, const float* __restrict__ resw,
    int K) {
    __shared__ __align__(16) short SB[2][4][128][32];   // 64 KB, double-buffered
    const int tid = threadIdx.x;
    const int rowBase = blockIdx.y * 128;
    const int colBase = blockIdx.x * 128;
    const int wave = tid >> 6, lane = tid & 63;
    const int wm = (wave & 1) * 64, wn = (wave >> 1) * 64;
    const int lm = lane & 15;
    const int psl8 = ((lane >> 4) ^ ((lm >> 1) & 3)) * 8;   // swizzled 16B slot for reads

    // staging source for this wave's plane
    const bf16* src = (wave == 0) ? Ah : (wave == 1) ? Al : (wave == 2) ? Wh : Wl;
    const int sld = (wave < 2) ? lda : ldw;
    const int srb = (wave < 2) ? rowBase : colBase;
    const int sslot = (lane & 3) ^ ((lane >> 3) & 3);       // pre-swizzled source slot
    const bf16* sp = src + (size_t)(srb + (lane >> 2)) * sld + sslot * 8;
    short* lb0 = &SB[0][wave][0][0];
    short* lb1 = &SB[1][wave][0][0];

    f32x4 acc[4][4];
#pragma unroll
    for (int i = 0; i < 4; ++i)
#pragma unroll
        for (int j = 0; j < 4; ++j)
            acc[i][j] = (f32x4){0.f, 0.f, 0.f, 0.f};

    const int nt = K >> 5;
    // prologue: stage tiles 0 and 1
#pragma unroll
    for (int j = 0; j < 8; ++j)
        gll16(sp + (size_t)j * 16 * sld, lb0 + j * 512);
    {
        const bf16* p = sp + 32;
#pragma unroll
        for (int j = 0; j < 8; ++j)
            gll16(p + (size_t)j * 16 * sld, lb1 + j * 512);
    }
    for (int t = 0; t < nt; ++t) {
        const int cur = t & 1;
        if (t + 1 < nt) asm volatile("s_waitcnt vmcnt(8)" ::: "memory");
        else            asm volatile("s_waitcnt vmcnt(0)" ::: "memory");
        __builtin_amdgcn_s_barrier();
        __builtin_amdgcn_sched_barrier(0);
        const short (*P)[128][32] = SB[cur];
        short8 ah[4], al[4], wh[4], wl[4];
#pragma unroll
        for (int i = 0; i < 4; ++i) {
            ah[i] = *(const short8*)&P[0][wm + i * 16 + lm][psl8];
            al[i] = *(const short8*)&P[1][wm + i * 16 + lm][psl8];
            wh[i] = *(const short8*)&P[2][wn + i * 16 + lm][psl8];
            wl[i] = *(const short8*)&P[3][wn + i * 16 + lm][psl8];
        }
#pragma unroll
        for (int i = 0; i < 4; ++i)
#pragma unroll
            for (int j = 0; j < 4; ++j)
                acc[i][j] = __builtin_amdgcn_mfma_f32_16x16x32_bf16(ah[i], wh[j], acc[i][j], 0, 0, 0);
#pragma unroll
        for (int i = 0; i < 4; ++i)
#pragma unroll
            for (int j = 0; j < 4; ++j)
                acc[i][j] = __builtin_amdgcn_mfma_f32_16x16x32_bf16(ah[i], wl[j], acc[i][j], 0, 0, 0);
#pragma unroll
        for (int i = 0; i < 4; ++i)
#pragma unroll
            for (int j = 0; j < 4; ++j)
                acc[i][j] = __builtin_amdgcn_mfma_f32_16x16x32_bf16(al[i], wh[j], acc[i][j], 0, 0, 0);
        __builtin_amdgcn_s_barrier();      // all waves done reading SB[cur]
        if (t + 2 < nt) {                  // refill SB[cur] with tile t+2
            short* lb = cur ? lb1 : lb0;
            const bf16* p = sp + (t + 2) * 32;
#pragma unroll
            for (int j = 0; j < 8; ++j)
                gll16(p + (size_t)j * 16 * sld, lb + j * 512);
        }
    }

    // epilogue: C/D layout col = lane&15, row = (lane>>4)*4 + reg
    float bv[4];
#pragma unroll
    for (int j = 0; j < 4; ++j)
        bv[j] = bias ? bias[colBase + wn + j * 16 + lm] : 0.f;
    float scv = 0.f;
    if (OUT == 3) scv = resw[0];
#pragma unroll
    for (int i = 0; i < 4; ++i) {
#pragma unroll
        for (int reg = 0; reg < 4; ++reg) {
            const int r = rowBase + wm + i * 16 + (lane >> 4) * 4 + reg;
            int tok = 0, srow = 0;
            if (OUT == 3) { tok = noisy[r]; srow = r % SEQ; }
#pragma unroll
            for (int j = 0; j < 4; ++j) {
                const int col = colBase + wn + j * 16 + lm;
                float v = acc[i][j][reg] + bv[j];
                if (OUT == 0) {
                    C[(size_t)r * ldc + col] = v;
                } else if (OUT == 1) {
                    float* cp = C + (size_t)r * ldc + col;
                    *cp = *cp + v;
                } else if (OUT == 2) {
                    v = gelu_f(v);
                    split_store(v, Ohi, Olo, (size_t)r * ldp + col);
                } else if (OUT == 3) {
                    const float xv = cb[(size_t)tok * E + col] + pe[(size_t)srow * E + col];
                    v = xv + scv * v;
                    split_store(v, Ohi, Olo, (size_t)r * ldp + col);
                } else if (OUT == 4) {
                    split_store(v, Ohi, Olo, (size_t)r * ldp + col);
                } else { // OUT == 5
                    C[(size_t)r * ldc + col] = v;
                    split_store(v, Ohi, Olo, (size_t)r * ldp + col);
                }
            }
        }
    }
}

// ---------------------------------------------------------------- V transpose: qkv planes -> Vt[bh*64+d][s] (ld VLD)
__global__ __launch_bounds__(256) void vtrans(const bf16* __restrict__ vh_src,
                                              const bf16* __restrict__ vl_src,
                                              bf16* __restrict__ vth,
                                              bf16* __restrict__ vtl) {
    __shared__ short T[64][72];
    const int tid = threadIdx.x;
    const int st = blockIdx.x;   // 16 s-tiles of 64
    const int bh = blockIdx.y;   // 128
    const int b = bh >> 3, h = bh & 7;
    const int sr = tid >> 2, dq = (tid & 3) * 16;
    const int s_g = st * 64 + sr;
    const int od = tid >> 3;          // 0..31 (+32)
    const int osq = (tid & 7) * 8;    // 0..56
#pragma unroll
    for (int p = 0; p < 2; ++p) {
        const short* src = (const short*)(p ? vl_src : vh_src);
        short* dst = (short*)(p ? vtl : vth);
        short8 a0 = {0, 0, 0, 0, 0, 0, 0, 0};
        short8 a1 = {0, 0, 0, 0, 0, 0, 0, 0};
        if (s_g < SEQ) {
            const short* sp = src + (size_t)(b * SEQ + s_g) * 1536 + 1024 + h * 64 + dq;
            a0 = *(const short8*)sp;
            a1 = *(const short8*)(sp + 8);
        }
        __syncthreads();
#pragma unroll
        for (int j = 0; j < 8; ++j) T[dq + j][sr] = a0[j];
#pragma unroll
        for (int j = 0; j < 8; ++j) T[dq + 8 + j][sr] = a1[j];
        __syncthreads();
        const int scol = st * 64 + osq;
        if (scol + 8 <= VLD) {
            const short8 o0 = *(const short8*)&T[od][osq];
            const short8 o1 = *(const short8*)&T[od + 32][osq];
            *(short8*)(dst + (size_t)(bh * 64 + od) * VLD + scol) = o0;
            *(short8*)(dst + (size_t)(bh * 64 + od + 32) * VLD + scol) = o1;
        }
    }
}

// ---------------------------------------------------------------- MFMA flash attention (split bf16)
__global__ __launch_bounds__(256) void attn_mfma(const bf16* __restrict__ qkh,
                                                 const bf16* __restrict__ qkl,
                                                 const bf16* __restrict__ vth,
                                                 const bf16* __restrict__ vtl,
                                                 bf16* __restrict__ chi,
                                                 bf16* __restrict__ clo) {
    __shared__ short QPs[2][64][72];   // Q staging, then P
    __shared__ short Ks[2][64][72];
    __shared__ short Vs[2][64][72];    // Vt tile: [d][n]
    const int tid = threadIdx.x;
    const int qt = blockIdx.x, bh = blockIdx.y;
    const int b = bh >> 3, h = bh & 7;
    const int wave = tid >> 6, lane = tid & 63;
    const int lm = lane & 15, g = lane >> 4, q8 = g * 8;
    const int wq = wave * 16;
    const int r0 = tid >> 2, kq = (tid & 3) * 16;
    const short8 z = {0, 0, 0, 0, 0, 0, 0, 0};

    {
        const int q = qt * 64 + r0;
        short8 a0 = z, a1 = z, b0 = z, b1 = z;
        if (q < SEQ) {
            const size_t base = (size_t)(b * SEQ + q) * 1536 + h * 64 + kq;
            a0 = *(const short8*)((const short*)qkh + base);
            a1 = *(const short8*)((const short*)qkh + base + 8);
            b0 = *(const short8*)((const short*)qkl + base);
            b1 = *(const short8*)((const short*)qkl + base + 8);
        }
        *(short8*)&QPs[0][r0][kq] = a0; *(short8*)&QPs[0][r0][kq + 8] = a1;
        *(short8*)&QPs[1][r0][kq] = b0; *(short8*)&QPs[1][r0][kq + 8] = b1;
    }
    __syncthreads();
    short8 qfh[2], qfl[2];
#pragma unroll
    for (int t = 0; t < 2; ++t) {
        qfh[t] = *(const short8*)&QPs[0][wq + lm][t * 32 + q8];
        qfl[t] = *(const short8*)&QPs[1][wq + lm][t * 32 + q8];
    }

    float m_i[4] = {-3e38f, -3e38f, -3e38f, -3e38f};
    float l_i[4] = {0.f, 0.f, 0.f, 0.f};
    f32x4 o[4];
#pragma unroll
    for (int dt = 0; dt < 4; ++dt) o[dt] = (f32x4){0.f, 0.f, 0.f, 0.f};

    // K/V staging registers (prefetched one tile ahead)
    short8 ka0 = z, ka1 = z, kl0 = z, kl1 = z;
    short8 va0 = z, va1 = z, vl0 = z, vl1 = z;
    auto loadKV = [&](int kb2) {
        const int kr = kb2 + r0;
        ka0 = z; ka1 = z; kl0 = z; kl1 = z;
        if (kr < SEQ) {
            const size_t base = (size_t)(b * SEQ + kr) * 1536 + 512 + h * 64 + kq;
            ka0 = *(const short8*)((const short*)qkh + base);
            ka1 = *(const short8*)((const short*)qkh + base + 8);
            kl0 = *(const short8*)((const short*)qkl + base);
            kl1 = *(const short8*)((const short*)qkl + base + 8);
        }
        const size_t vbase = (size_t)(bh * 64 + r0) * VLD + kb2 + kq;
        va0 = z; va1 = z; vl0 = z; vl1 = z;
        if (kb2 + kq + 8 <= VLD) {
            va0 = *(const short8*)((const short*)vth + vbase);
            vl0 = *(const short8*)((const short*)vtl + vbase);
        }
        if (kb2 + kq + 16 <= VLD) {
            va1 = *(const short8*)((const short*)vth + vbase + 8);
            vl1 = *(const short8*)((const short*)vtl + vbase + 8);
        }
    };
    loadKV(0);

    for (int kb = 0; kb < SEQ; kb += 64) {
        __syncthreads();
        {
            *(short8*)&Ks[0][r0][kq] = ka0; *(short8*)&Ks[0][r0][kq + 8] = ka1;
            *(short8*)&Ks[1][r0][kq] = kl0; *(short8*)&Ks[1][r0][kq + 8] = kl1;
            *(short8*)&Vs[0][r0][kq] = va0; *(short8*)&Vs[0][r0][kq + 8] = va1;
            *(short8*)&Vs[1][r0][kq] = vl0; *(short8*)&Vs[1][r0][kq + 8] = vl1;
        }
        __syncthreads();
        if (kb + 64 < SEQ) loadKV(kb + 64);   // prefetch: overlaps QK^T + softmax
        f32x4 sac[4];
#pragma unroll
        for (int j = 0; j < 4; ++j) sac[j] = (f32x4){0.f, 0.f, 0.f, 0.f};
#pragma unroll
        for (int t = 0; t < 2; ++t) {
#pragma unroll
            for (int j = 0; j < 4; ++j) {
                const short8 kh = *(const short8*)&Ks[0][j * 16 + lm][t * 32 + q8];
                const short8 kl = *(const short8*)&Ks[1][j * 16 + lm][t * 32 + q8];
                sac[j] = __builtin_amdgcn_mfma_f32_16x16x32_bf16(qfh[t], kh, sac[j], 0, 0, 0);
                sac[j] = __builtin_amdgcn_mfma_f32_16x16x32_bf16(qfh[t], kl, sac[j], 0, 0, 0);
                sac[j] = __builtin_amdgcn_mfma_f32_16x16x32_bf16(qfl[t], kh, sac[j], 0, 0, 0);
            }
        }
        float alpha_v[4];
#pragma unroll
        for (int reg = 0; reg < 4; ++reg) {
            float sv[4];
            float rm = -3e38f;
#pragma unroll
            for (int j = 0; j < 4; ++j) {
                const int kc = kb + j * 16 + lm;
                float s = sac[j][reg] * 0.125f;
                s = (kc < SEQ) ? s : -3e38f;
                sv[j] = s;
                rm = fmaxf(rm, s);
            }
#pragma unroll
            for (int m = 1; m < 16; m <<= 1) rm = fmaxf(rm, __shfl_xor(rm, m));
            const float mn = fmaxf(m_i[reg], rm);
            const float al = expf(m_i[reg] - mn);
            float rs = 0.f;
            const int prow = wq + g * 4 + reg;
#pragma unroll
            for (int j = 0; j < 4; ++j) {
                const float pv = expf(sv[j] - mn);
                rs += pv;
                bf16 phb = __float2bfloat16(pv);
                bf16 plb = __float2bfloat16(pv - __bfloat162float(phb));
                QPs[0][prow][j * 16 + lm] = *reinterpret_cast<short*>(&phb);
                QPs[1][prow][j * 16 + lm] = *reinterpret_cast<short*>(&plb);
            }
#pragma unroll
            for (int m = 1; m < 16; m <<= 1) rs += __shfl_xor(rs, m);
            l_i[reg] = l_i[reg] * al + rs;
            m_i[reg] = mn;
            alpha_v[reg] = al;
        }
        const f32x4 av = {alpha_v[0], alpha_v[1], alpha_v[2], alpha_v[3]};
#pragma unroll
        for (int dt = 0; dt < 4; ++dt) o[dt] *= av;
        __syncthreads();
#pragma unroll
        for (int t = 0; t < 2; ++t) {
            const short8 ph = *(const short8*)&QPs[0][wq + lm][t * 32 + q8];
            const short8 pl = *(const short8*)&QPs[1][wq + lm][t * 32 + q8];
#pragma unroll
            for (int dt = 0; dt < 4; ++dt) {
                const short8 vh = *(const short8*)&Vs[0][dt * 16 + lm][t * 32 + q8];
                const short8 vl = *(const short8*)&Vs[1][dt * 16 + lm][t * 32 + q8];
                o[dt] = __builtin_amdgcn_mfma_f32_16x16x32_bf16(ph, vh, o[dt], 0, 0, 0);
                o[dt] = __builtin_amdgcn_mfma_f32_16x16x32_bf16(ph, vl, o[dt], 0, 0, 0);
                o[dt] = __builtin_amdgcn_mfma_f32_16x16x32_bf16(pl, vh, o[dt], 0, 0, 0);
            }
        }
    }
#pragma unroll
    for (int reg = 0; reg < 4; ++reg) {
        const int q = qt * 64 + wq + g * 4 + reg;
        if (q < SEQ) {
            const float inv = 1.0f / l_i[reg];
#pragma unroll
            for (int dt = 0; dt < 4; ++dt) {
                const size_t idx = (size_t)(b * SEQ + q) * E + h * 64 + dt * 16 + lm;
                split_store(o[dt][reg] * inv, chi, clo, idx);
            }
        }
    }
}

// ---------------------------------------------------------------- codebook row norms
__global__ __launch_bounds__(256) void cbnorm_kernel(const float* __restrict__ cb,
                                                     float* __restrict__ out) {
    const int lane = threadIdx.x & 63;
    const int row = blockIdx.x * 4 + (threadIdx.x >> 6);
    const float* p = cb + (size_t)row * E;
    const float4 v0 = *(const float4*)(p + lane * 4);
    const float4 v1 = *(const float4*)(p + 256 + lane * 4);
    float sq = v0.x * v0.x + v0.y * v0.y + v0.z * v0.z + v0.w * v0.w
             + v1.x * v1.x + v1.y * v1.y + v1.z * v1.z + v1.w * v1.w;
#pragma unroll
    for (int m = 1; m < 64; m <<= 1) sq += __shfl_xor(sq, m);
    if (lane == 0) out[row] = sq;
}

// ---------------------------------------------------------------- stage A: split-bf16 MFMA distance, A-in-registers (pinned)
// 250 blocks x 512 threads (8 waves = 4 row-groups x 2 col-halves; 2 waves/SIMD).
// Each wave owns 16 fc rows; lane holds its A frags in regs (a_h[16], a_l[16]),
// PINNED via asm "+v" so the compiler cannot rematerialize the global loads
// (R5 evidence: VGPR=120 < 128 needed -> A was being reloaded every step).
// W (cb planes) streams through a 32KB LDS double buffer, counted vmcnt(2).
// Wave computes its 64-col half (j = chalf*4..+3, 12 MFMA/step).
// part[row] = (v1, idx1, v2, idx2)
__global__ __launch_bounds__(512) void argmin_mfma(
    const bf16* __restrict__ Ah, const bf16* __restrict__ Al,
    const bf16* __restrict__ Wh, const bf16* __restrict__ Wl,
    const float* __restrict__ cbn, float4* __restrict__ part) {
    __shared__ __align__(16) short Wreg[2][8192];   // 32 KB: [buf][(plane*128+col)*32]
    const int tid = threadIdx.x;
    const int rowBase = blockIdx.x * 64;
    const int wave = tid >> 6, lane = tid & 63;
    const int rowg = wave & 3;        // 16-row group
    const int chalf = wave >> 2;      // 64-col half (j offset 0 / 4)
    const int lm = lane & 15, g = lane >> 4;
    const int g8 = g * 8;
    const int psl8 = (g ^ ((lm >> 1) & 3)) * 8;
    const int sslot = (lane & 3) ^ ((lane >> 3) & 3);
    const int srow = lane >> 2;
    const int row = rowBase + rowg * 16 + lm;   // the A row this lane's frags cover

    // ---- A -> registers (once): 16 k-chunks x 2 planes, 16B frag each.
    short8 a_h[16], a_l[16];
#pragma unroll
    for (int c = 0; c < 16; ++c) {
        a_h[c] = *(const short8*)(Ah + (size_t)row * E + c * 32 + g8);
        a_l[c] = *(const short8*)(Al + (size_t)row * E + c * 32 + g8);
    }
    // pin: opaque redefinition forbids rematerializing the loads (rule #17/#20)
#pragma unroll
    for (int c = 0; c < 16; ++c) {
        asm volatile("" : "+v"(a_h[c]));
        asm volatile("" : "+v"(a_l[c]));
    }

    // ---- W staging: tile s (ct = s>>4 col-tile, k = s&15) -> buf s&1.
    // 16 pieces of 1KB; 8 waves stage 2 each -> vmcnt granularity = 2/wave.
    auto stageW = [&](int s) {
        const int ct = s >> 4, k = s & 15;
        const int colB = ct * 128;
        short* dstb = &Wreg[s & 1][0];
#pragma unroll
        for (int e = 0; e < 2; ++e) {
            const int m = wave * 2 + e;   // 0..15
            const int p = m >> 3;         // plane
            const int j = m & 7;          // 16-col group
            const bf16* srcp = p ? Wl : Wh;
            gll16(srcp + (size_t)(colB + j * 16 + srow) * E + k * 32 + sslot * 8,
                  dstb + ((p * 128 + j * 16) * 32));
        }
    };
    stageW(0);
    stageW(1);

    float rv1[4], rv2[4];
    int rc1[4], rc2[4];
#pragma unroll
    for (int r = 0; r < 4; ++r) {
        rv1[r] = 3e38f; rv2[r] = 3e38f;
        rc1[r] = 0x7fffffff; rc2[r] = 0x7fffffff;
    }
    f32x4 acc[4];
#pragma unroll
    for (int j = 0; j < 4; ++j) acc[j] = (f32x4){0.f, 0.f, 0.f, 0.f};

    for (int ct = 0; ct < 32; ++ct) {
        const int colB = ct * 128;
#pragma unroll
        for (int k = 0; k < 16; ++k) {      // full unroll: a_h[k]/a_l[k] static
            const int s = ct * 16 + k;
            if (s + 1 < 512) asm volatile("s_waitcnt vmcnt(2)" ::: "memory");
            else             asm volatile("s_waitcnt vmcnt(0)" ::: "memory");
            __builtin_amdgcn_s_barrier();
            __builtin_amdgcn_sched_barrier(0);
            const short* B = &Wreg[s & 1][0];
#pragma unroll
            for (int j = 0; j < 4; ++j) {
                const int jj = chalf * 4 + j;
                const short8 wh = *(const short8*)(B + (jj * 16 + lm) * 32 + psl8);
                const short8 wl = *(const short8*)(B + (128 + jj * 16 + lm) * 32 + psl8);
                acc[j] = __builtin_amdgcn_mfma_f32_16x16x32_bf16(a_h[k], wh, acc[j], 0, 0, 0);
                acc[j] = __builtin_amdgcn_mfma_f32_16x16x32_bf16(a_h[k], wl, acc[j], 0, 0, 0);
                acc[j] = __builtin_amdgcn_mfma_f32_16x16x32_bf16(a_l[k], wh, acc[j], 0, 0, 0);
            }
            __builtin_amdgcn_s_barrier();     // all waves done reading Wreg[s&1]
            if (s + 2 < 512) stageW(s + 2);   // refill Wreg[s&1] with tile s+2
        }
        // ct finished: fold this wave's 64 cols into per-lane running top2
#pragma unroll
        for (int j = 0; j < 4; ++j) {
            const int col = colB + (chalf * 4 + j) * 16 + lm;
            const float nv = cbn[col];
#pragma unroll
            for (int r = 0; r < 4; ++r) {
                const float d = nv - 2.0f * acc[j][r];
                t2_ins(d, col, rv1[r], rc1[r], rv2[r], rc2[r]);
            }
            acc[j] = (f32x4){0.f, 0.f, 0.f, 0.f};
        }
    }

    // ---- merge across the 16 lm lanes of each g group
#pragma unroll
    for (int r = 0; r < 4; ++r) {
#pragma unroll
        for (int m = 1; m < 16; m <<= 1) {
            const float w1 = __shfl_xor(rv1[r], m); const int d1 = __shfl_xor(rc1[r], m);
            const float w2 = __shfl_xor(rv2[r], m); const int d2 = __shfl_xor(rc2[r], m);
            t2_ins(w1, d1, rv1[r], rc1[r], rv2[r], rc2[r]);
            t2_ins(w2, d2, rv1[r], rc1[r], rv2[r], rc2[r]);
        }
    }
    // ---- cross-half merge via dead W LDS (no DMA in flight: last stage guarded)
    __syncthreads();
    float4* mbuf = reinterpret_cast<float4*>(&Wreg[0][0]);  // [64 rows][2 halves]
    if (lm == 0) {
#pragma unroll
        for (int r = 0; r < 4; ++r)
            mbuf[(rowg * 16 + g * 4 + r) * 2 + chalf] =
                make_float4(rv1[r], (float)rc1[r], rv2[r], (float)rc2[r]);
    }
    __syncthreads();
    if (tid < 64) {
        const float4 p0 = mbuf[tid * 2 + 0];
        const float4 p1 = mbuf[tid * 2 + 1];
        float v1 = p0.x, v2 = p0.z;
        int c1 = (int)p0.y, c2 = (int)p0.w;
        t2_ins(p1.x, (int)p1.y, v1, c1, v2, c2);
        t2_ins(p1.z, (int)p1.w, v1, c1, v2, c2);
        part[rowBase + tid] = make_float4(v1, (float)c1, v2, (float)c2);
    }
}

// ---------------------------------------------------------------- stage B: exact fp32 rescore of top2
__global__ __launch_bounds__(256) void argmin_exact(const float4* __restrict__ part,
                                                    const float* __restrict__ fc,
                                                    const float* __restrict__ cb,
                                                    const float* __restrict__ cbn,
                                                    float* __restrict__ tokf) {
    const int wave = threadIdx.x >> 6, lane = threadIdx.x & 63;
    const int r = blockIdx.x * 4 + wave;   // 4000 blocks
    const float4 p = part[r];
    const int c1 = (int)p.y;
    const int c2 = (int)p.w;
    // exact fp32 d2 for c1, c2
    const float* fr = fc + (size_t)r * E + lane * 8;
    const float* p1 = cb + (size_t)c1 * E + lane * 8;
    const float* p2 = cb + (size_t)c2 * E + lane * 8;
    float d1 = 0.f, d2 = 0.f;
#pragma unroll
    for (int j = 0; j < 8; ++j) {
        const float f = fr[j];
        d1 += f * p1[j];
        d2 += f * p2[j];
    }
#pragma unroll
    for (int m = 1; m < 64; m <<= 1) {
        d1 += __shfl_xor(d1, m);
        d2 += __shfl_xor(d2, m);
    }
    d1 = cbn[c1] - 2.0f * d1;
    d2 = cbn[c2] - 2.0f * d2;
    const int win = ((d1 < d2) || (d1 == d2 && c1 < c2)) ? c1 : c2;
    if (lane == 0) tokf[r] = (float)win;
}

// ---------------------------------------------------------------- launch
extern "C" void kernel_launch(void* const* d_in, const int* in_sizes, int n_in,
                              void* d_out, int out_size, void* d_ws, size_t ws_size,
                              hipStream_t stream) {
    const int* noisy = (const int*)d_in[0];
    const float* codebook = (const float*)d_in[1];
    const float* pos_enc = (const float*)d_in[2];
    const float* qkv_w = (const float*)d_in[3];
    const float* qkv_b = (const float*)d_in[4];
    const float* out_w = (const float*)d_in[5];
    const float* out_b = (const float*)d_in[6];
    const float* ln1_g = (const float*)d_in[7];
    const float* ln1_b = (const float*)d_in[8];
    const float* ln2_g = (const float*)d_in[9];
    const float* ln2_b = (const float*)d_in[10];
    const float* ff1_w = (const float*)d_in[11];
    const float* ff1_b = (const float*)d_in[12];
    const float* ff2_w = (const float*)d_in[13];
    const float* ff2_b = (const float*)d_in[14];
    const float* fin_g = (const float*)d_in[15];
    const float* fin_b = (const float*)d_in[16];
    const float* pp1_w = (const float*)d_in[17];
    const float* pp1_b = (const float*)d_in[18];
    const float* pp_ln_g = (const float*)d_in[19];
    const float* pp_ln_b = (const float*)d_in[20];
    const float* pp2_w = (const float*)d_in[21];
    const float* pp2_b = (const float*)d_in[22];
    const float* res_w = (const float*)d_in[23];
    const float* fc1_w = (const float*)d_in[24];
    const float* fc1_b = (const float*)d_in[25];
    const float* fc_ln_g = (const float*)d_in[26];
    const float* fc_ln_b = (const float*)d_in[27];
    const float* fc2_w = (const float*)d_in[28];
    const float* fc2_b = (const float*)d_in[29];

    // workspace (floats), total 41,025,536 floats = 164.1 MB
    float* ws = (float*)d_ws;
    float* y = ws;                        // [0, 8.192M)
    float* REG = ws + 8192000;            // [8.192M, 32.768M)
    bf16* qkvh = (bf16*)REG;              // 16000x1536 shorts
    bf16* qkvl = qkvh + 24576000;
    bf16* mid_hi = (bf16*)REG;            // FF phase: 16000x1024
    bf16* mid_lo = mid_hi + 16384000;
    float* slotA = REG;                   // tail: e planes / fc fp32
    float* slotB = REG + 8192000;         // tail: pp1/fc1 fp32 tmp, then cbn+partials
    bf16* e_hi = (bf16*)slotA;
    bf16* e_lo = e_hi + 8192000;
    bf16* fcp2_hi = (bf16*)(REG + 16384000);  // fc planes (spare tail region)
    bf16* fcp2_lo = fcp2_hi + 8192000;
    float* WV = ws + 32768000;            // [32.768M, 41.0255M): Vt planes OR weight splits OR cb planes
    bf16* vth = (bf16*)WV;                // 8192 x VLD
    bf16* vtl = vth + 8192 * VLD;
    bf16* wA_hi = (bf16*)WV;              // cap 2048x512 each
    bf16* wA_lo = wA_hi + 1048576;
    bf16* wB_hi = wA_lo + 1048576;
    bf16* wB_lo = wB_hi + 1048576;
    bf16* cbh = wB_lo + 1048576;          // 4096x512, after weights (tail only)
    bf16* cbl = cbh + 2097152;
    float* cbn = slotB;                   // tail-only
    float4* part = (float4*)(slotB + 4096);  // 16000 float4
    // h planes live in d_out (dead before final outputs are written)
    bf16* h_hi = (bf16*)d_out;
    bf16* h_lo = h_hi + 8192000;
    float* tokf = (float*)d_out + 8192000;

    const dim3 blk(256);
    const dim3 g512(4, 125), g1024(8, 125), g1536(12, 125);

    embed_kernel<<<dim3(NTOK), dim3(128), 0, stream>>>(noisy, codebook, pos_enc, y);

    for (int l = 0; l < 4; ++l) {
        ln_planes<0><<<dim3(4000), blk, 0, stream>>>(y, h_hi, h_lo, ln1_g + l * E, ln1_b + l * E);
        split_w<<<dim3(3072), blk, 0, stream>>>(qkv_w + (size_t)l * 1536 * E, E, 9, 1536 * E, wA_hi, wA_lo);
        gemm_split<4><<<g1536, blk, 0, stream>>>(
            h_hi, h_lo, E, wA_hi, wA_lo, E, qkv_b + (size_t)l * 1536,
            nullptr, 0, qkvh, qkvl, 1536, nullptr, nullptr, nullptr, nullptr, E);
        vtrans<<<dim3(16, 128), blk, 0, stream>>>(qkvh, qkvl, vth, vtl);  // overwrites wA (dead)
        attn_mfma<<<dim3(16, 128), blk, 0, stream>>>(qkvh, qkvl, vth, vtl, h_hi, h_lo);
        split_w<<<dim3(1024), blk, 0, stream>>>(out_w + (size_t)l * E * E, E, 9, E * E, wB_hi, wB_lo);
        gemm_split<1><<<g512, blk, 0, stream>>>(
            h_hi, h_lo, E, wB_hi, wB_lo, E, out_b + (size_t)l * E,
            y, E, nullptr, nullptr, 0, nullptr, nullptr, nullptr, nullptr, E);
        ln_planes<0><<<dim3(4000), blk, 0, stream>>>(y, h_hi, h_lo, ln2_g + l * E, ln2_b + l * E);
        split_w<<<dim3(4096), blk, 0, stream>>>(ff1_w + (size_t)l * FFD * E, E, 9, FFD * E, wA_hi, wA_lo);
        split_w<<<dim3(4096), blk, 0, stream>>>(ff2_w + (size_t)l * E * FFD, FFD, 11, E * FFD, wB_hi, wB_lo);
        for (int c = 0; c < 2; ++c) {
            gemm_split<2><<<g1024, blk, 0, stream>>>(
                h_hi, h_lo, E, wA_hi + (size_t)c * 1024 * E, wA_lo + (size_t)c * 1024 * E, E,
                ff1_b + (size_t)l * FFD + c * 1024,
                nullptr, 0, mid_hi, mid_lo, 1024, nullptr, nullptr, nullptr, nullptr, E);
            gemm_split<1><<<g512, blk, 0, stream>>>(
                mid_hi, mid_lo, 1024, wB_hi + c * 1024, wB_lo + c * 1024, FFD,
                (c == 0) ? (ff2_b + (size_t)l * E) : nullptr,
                y, E, nullptr, nullptr, 0, nullptr, nullptr, nullptr, nullptr, 1024);
        }
    }

    // tail
    ln_planes<0><<<dim3(4000), blk, 0, stream>>>(y, h_hi, h_lo, fin_g, fin_b);
    split_w<<<dim3(1024), blk, 0, stream>>>(pp1_w, E, 9, E * E, wA_hi, wA_lo);
    gemm_split<0><<<g512, blk, 0, stream>>>(
        h_hi, h_lo, E, wA_hi, wA_lo, E, pp1_b,
        slotB, E, nullptr, nullptr, 0, nullptr, nullptr, nullptr, nullptr, E);
    ln_planes<1><<<dim3(4000), blk, 0, stream>>>(slotB, h_hi, h_lo, pp_ln_g, pp_ln_b);
    split_w<<<dim3(1024), blk, 0, stream>>>(pp2_w, E, 9, E * E, wB_hi, wB_lo);
    gemm_split<3><<<g512, blk, 0, stream>>>(
        h_hi, h_lo, E, wB_hi, wB_lo, E, pp2_b,
        nullptr, 0, e_hi, e_lo, E, noisy, codebook, pos_enc, res_w, E);
    split_w<<<dim3(1024), blk, 0, stream>>>(fc1_w, E, 9, E * E, wA_hi, wA_lo);
    gemm_split<0><<<g512, blk, 0, stream>>>(
        e_hi, e_lo, E, wA_hi, wA_lo, E, fc1_b,
        slotB, E, nullptr, nullptr, 0, nullptr, nullptr, nullptr, nullptr, E);
    ln_planes<1><<<dim3(4000), blk, 0, stream>>>(slotB, h_hi, h_lo, fc_ln_g, fc_ln_b);
    split_w<<<dim3(1024), blk, 0, stream>>>(fc2_w, E, 9, E * E, wB_hi, wB_lo);
    gemm_split<5><<<g512, blk, 0, stream>>>(
        h_hi, h_lo, E, wB_hi, wB_lo, E, fc2_b,
        slotA, E, fcp2_hi, fcp2_lo, E, nullptr, nullptr, nullptr, nullptr, E);  // fc fp32 + planes

    // argmin: A-in-registers (pinned) MFMA top2 + exact fp32 rescore
    split_w<<<dim3(8192), blk, 0, stream>>>(codebook, E, 9, CBN * E, cbh, cbl);
    cbnorm_kernel<<<dim3(1024), blk, 0, stream>>>(codebook, cbn);
    argmin_mfma<<<dim3(250), dim3(512), 0, stream>>>(fcp2_hi, fcp2_lo, cbh, cbl, cbn, part);
    argmin_exact<<<dim3(4000), blk, 0, stream>>>(part, slotA, codebook, cbn, tokf);
    hipMemcpyAsync(d_out, slotA, (size_t)8192000 * 4, hipMemcpyDeviceToDevice, stream);
}

// Round 8
// 3392.110 us; speedup vs baseline: 1.0799x; 1.0462x over previous
//
#include <hip/hip_runtime.h>
#include <hip/hip_bf16.h>
#include <math.h>

#define NTOK 16000
#define E    512
#define FFD  2048
#define CBN  4096
#define SEQ  1000
#define NH   8
#define VLD  1008   // Vt padded leading dim (s), multiple of 8

typedef __hip_bfloat16 bf16;
typedef __attribute__((ext_vector_type(8))) short short8;
typedef __attribute__((ext_vector_type(4))) float f32x4;

__device__ __forceinline__ float gelu_f(float v) {
    return 0.5f * v * (1.0f + erff(v * 0.70710678118654752f));
}

__device__ __forceinline__ void split_store(float v, bf16* hi, bf16* lo, size_t idx) {
    bf16 h = __float2bfloat16(v);
    hi[idx] = h;
    lo[idx] = __float2bfloat16(v - __bfloat162float(h));
}

// async global->LDS, 16B per lane. LDS dest is wave-uniform base + lane*16.
__device__ __forceinline__ void gll16(const bf16* g, short* l) {
    __builtin_amdgcn_global_load_lds((const __attribute__((address_space(1))) void*)g,
                                     (__attribute__((address_space(3))) void*)l, 16, 0, 0);
}

// top-2 insert with np.argmin tiebreak (smaller index wins on equal value)
__device__ __forceinline__ void t2_ins(float v, int c, float& v1, int& c1, float& v2, int& c2) {
    const bool b1 = (v < v1) || (v == v1 && c < c1);
    const bool b2 = (v < v2) || (v == v2 && c < c2);
    if (b1) { v2 = v1; c2 = c1; v1 = v; c1 = c; }
    else if (b2) { v2 = v; c2 = c; }
}

// ---------------------------------------------------------------- embed -> y (fp32)
__global__ __launch_bounds__(128) void embed_kernel(const int* __restrict__ tok,
                                                    const float* __restrict__ cb,
                                                    const float* __restrict__ pe,
                                                    float* __restrict__ y) {
    const int row = blockIdx.x;
    const int s = row % SEQ;
    const int t = tok[row];
    const int c = threadIdx.x * 4;
    const float4 cv = *(const float4*)(cb + (size_t)t * E + c);
    const float4 pv = *(const float4*)(pe + (size_t)s * E + c);
    *(float4*)(y + (size_t)row * E + c) =
        make_float4(cv.x + pv.x, cv.y + pv.y, cv.z + pv.z, cv.w + pv.w);
}

// ---------------------------------------------------------------- weight split fp32 -> hi/lo bf16 (compact dst)
__global__ __launch_bounds__(256) void split_w(const float* __restrict__ src, int ld,
                                               int cols_log2, int n,
                                               bf16* __restrict__ hi, bf16* __restrict__ lo) {
    const int i = blockIdx.x * 256 + threadIdx.x;
    if (i >= n) return;
    const int r = i >> cols_log2;
    const int c = i & ((1 << cols_log2) - 1);
    const float v = src[(size_t)r * ld + c];
    split_store(v, hi, lo, i);
}

// ---------------------------------------------------------------- layernorm -> hi/lo planes (1 wave/row)
template<int GELU>
__global__ __launch_bounds__(256) void ln_planes(const float* __restrict__ in,
                                                 bf16* __restrict__ hi, bf16* __restrict__ lo,
                                                 const float* __restrict__ g,
                                                 const float* __restrict__ b) {
    const int lane = threadIdx.x & 63;
    const int row = blockIdx.x * 4 + (threadIdx.x >> 6);
    const float* p = in + (size_t)row * E;
    const float4 v0 = *(const float4*)(p + lane * 4);
    const float4 v1 = *(const float4*)(p + 256 + lane * 4);
    float sum = v0.x + v0.y + v0.z + v0.w + v1.x + v1.y + v1.z + v1.w;
    float sq = v0.x * v0.x + v0.y * v0.y + v0.z * v0.z + v0.w * v0.w
             + v1.x * v1.x + v1.y * v1.y + v1.z * v1.z + v1.w * v1.w;
#pragma unroll
    for (int m = 1; m < 64; m <<= 1) {
        sum += __shfl_xor(sum, m);
        sq += __shfl_xor(sq, m);
    }
    const float mean = sum * (1.0f / 512.0f);
    const float var = sq * (1.0f / 512.0f) - mean * mean;
    const float rstd = rsqrtf(var + 1e-5f);
    const float4 g0 = *(const float4*)(g + lane * 4);
    const float4 g1 = *(const float4*)(g + 256 + lane * 4);
    const float4 b0 = *(const float4*)(b + lane * 4);
    const float4 b1 = *(const float4*)(b + 256 + lane * 4);
    const size_t base = (size_t)row * E;
    float o;
    const float vv0[4] = {v0.x, v0.y, v0.z, v0.w};
    const float gg0[4] = {g0.x, g0.y, g0.z, g0.w};
    const float bb0[4] = {b0.x, b0.y, b0.z, b0.w};
    const float vv1[4] = {v1.x, v1.y, v1.z, v1.w};
    const float gg1[4] = {g1.x, g1.y, g1.z, g1.w};
    const float bb1[4] = {b1.x, b1.y, b1.z, b1.w};
#pragma unroll
    for (int t = 0; t < 4; ++t) {
        o = (vv0[t] - mean) * rstd * gg0[t] + bb0[t];
        if (GELU) o = gelu_f(o);
        split_store(o, hi, lo, base + lane * 4 + t);
        o = (vv1[t] - mean) * rstd * gg1[t] + bb1[t];
        if (GELU) o = gelu_f(o);
        split_store(o, hi, lo, base + 256 + lane * 4 + t);
    }
}

// ---------------------------------------------------------------- split-bf16 MFMA NT GEMM
// C[M,N] = A[M,:]·W[N,:]^T via AhWh + AhWl + AlWh
// 128x128 tile, BK=32, 256 threads = 4 waves (2x2 of 64x64)
// Double-buffered global_load_lds staging with COUNTED vmcnt across raw
// barriers (T4): next tile's 8 DMAs stay in flight across the barrier.
// OUT: 0 = C fp32 (+bias); 1 = C += (+bias); 2 = gelu -> planes;
//      3 = emb(r,c) + resw*(v+bias) -> planes; 4 = plain -> planes;
//      5 = C fp32 AND planes
template<int OUT>
__global__ __launch_bounds__(256) void gemm_split(
    const bf16* __restrict__ Ah, const bf16* __restrict__ Al, int lda,
    const bf16* __restrict__ Wh, const bf16* __restrict__ Wl, int ldw,
    const float* __restrict__ bias,
    float* __restrict__ C, int ldc,
    bf16* __restrict__ Ohi, bf16* __restrict__ Olo, int ldp,
    const int* __restrict__ noisy, const float* __restrict__ cb,
    const float* __restrict__ pe, const float* __restrict__ resw,
    int K) {
    __shared__ __align__(16) short SB[2][4][128][32];   // 64 KB, double-buffered
    const int tid = threadIdx.x;
    const int rowBase = blockIdx.y * 128;
    const int colBase = blockIdx.x * 128;
    const int wave = tid >> 6, lane = tid & 63;
    const int wm = (wave & 1) * 64, wn = (wave >> 1) * 64;
    const int lm = lane & 15;
    const int psl8 = ((lane >> 4) ^ ((lm >> 1) & 3)) * 8;   // swizzled 16B slot for reads

    // staging source for this wave's plane
    const bf16* src = (wave == 0) ? Ah : (wave == 1) ? Al : (wave == 2) ? Wh : Wl;
    const int sld = (wave < 2) ? lda : ldw;
    const int srb = (wave < 2) ? rowBase : colBase;
    const int sslot = (lane & 3) ^ ((lane >> 3) & 3);       // pre-swizzled source slot
    const bf16* sp = src + (size_t)(srb + (lane >> 2)) * sld + sslot * 8;
    short* lb0 = &SB[0][wave][0][0];
    short* lb1 = &SB[1][wave][0][0];

    f32x4 acc[4][4];
#pragma unroll
    for (int i = 0; i < 4; ++i)
#pragma unroll
        for (int j = 0; j < 4; ++j)
            acc[i][j] = (f32x4){0.f, 0.f, 0.f, 0.f};

    const int nt = K >> 5;
    // prologue: stage tiles 0 and 1
#pragma unroll
    for (int j = 0; j < 8; ++j)
        gll16(sp + (size_t)j * 16 * sld, lb0 + j * 512);
    {
        const bf16* p = sp + 32;
#pragma unroll
        for (int j = 0; j < 8; ++j)
            gll16(p + (size_t)j * 16 * sld, lb1 + j * 512);
    }
    for (int t = 0; t < nt; ++t) {
        const int cur = t & 1;
        if (t + 1 < nt) asm volatile("s_waitcnt vmcnt(8)" ::: "memory");
        else            asm volatile("s_waitcnt vmcnt(0)" ::: "memory");
        __builtin_amdgcn_s_barrier();
        __builtin_amdgcn_sched_barrier(0);
        const short (*P)[128][32] = SB[cur];
        short8 ah[4], al[4], wh[4], wl[4];
#pragma unroll
        for (int i = 0; i < 4; ++i) {
            ah[i] = *(const short8*)&P[0][wm + i * 16 + lm][psl8];
            al[i] = *(const short8*)&P[1][wm + i * 16 + lm][psl8];
            wh[i] = *(const short8*)&P[2][wn + i * 16 + lm][psl8];
            wl[i] = *(const short8*)&P[3][wn + i * 16 + lm][psl8];
        }
#pragma unroll
        for (int i = 0; i < 4; ++i)
#pragma unroll
            for (int j = 0; j < 4; ++j)
                acc[i][j] = __builtin_amdgcn_mfma_f32_16x16x32_bf16(ah[i], wh[j], acc[i][j], 0, 0, 0);
#pragma unroll
        for (int i = 0; i < 4; ++i)
#pragma unroll
            for (int j = 0; j < 4; ++j)
                acc[i][j] = __builtin_amdgcn_mfma_f32_16x16x32_bf16(ah[i], wl[j], acc[i][j], 0, 0, 0);
#pragma unroll
        for (int i = 0; i < 4; ++i)
#pragma unroll
            for (int j = 0; j < 4; ++j)
                acc[i][j] = __builtin_amdgcn_mfma_f32_16x16x32_bf16(al[i], wh[j], acc[i][j], 0, 0, 0);
        __builtin_amdgcn_s_barrier();      // all waves done reading SB[cur]
        if (t + 2 < nt) {                  // refill SB[cur] with tile t+2
            short* lb = cur ? lb1 : lb0;
            const bf16* p = sp + (t + 2) * 32;
#pragma unroll
            for (int j = 0; j < 8; ++j)
                gll16(p + (size_t)j * 16 * sld, lb + j * 512);
        }
    }

    // epilogue: C/D layout col = lane&15, row = (lane>>4)*4 + reg
    float bv[4];
#pragma unroll
    for (int j = 0; j < 4; ++j)
        bv[j] = bias ? bias[colBase + wn + j * 16 + lm] : 0.f;
    float scv = 0.f;
    if (OUT == 3) scv = resw[0];
#pragma unroll
    for (int i = 0; i < 4; ++i) {
#pragma unroll
        for (int reg = 0; reg < 4; ++reg) {
            const int r = rowBase + wm + i * 16 + (lane >> 4) * 4 + reg;
            int tok = 0, srow = 0;
            if (OUT == 3) { tok = noisy[r]; srow = r % SEQ; }
#pragma unroll
            for (int j = 0; j < 4; ++j) {
                const int col = colBase + wn + j * 16 + lm;
                float v = acc[i][j][reg] + bv[j];
                if (OUT == 0) {
                    C[(size_t)r * ldc + col] = v;
                } else if (OUT == 1) {
                    float* cp = C + (size_t)r * ldc + col;
                    *cp = *cp + v;
                } else if (OUT == 2) {
                    v = gelu_f(v);
                    split_store(v, Ohi, Olo, (size_t)r * ldp + col);
                } else if (OUT == 3) {
                    const float xv = cb[(size_t)tok * E + col] + pe[(size_t)srow * E + col];
                    v = xv + scv * v;
                    split_store(v, Ohi, Olo, (size_t)r * ldp + col);
                } else if (OUT == 4) {
                    split_store(v, Ohi, Olo, (size_t)r * ldp + col);
                } else { // OUT == 5
                    C[(size_t)r * ldc + col] = v;
                    split_store(v, Ohi, Olo, (size_t)r * ldp + col);
                }
            }
        }
    }
}

// ---------------------------------------------------------------- V transpose: qkv planes -> Vt[bh*64+d][s] (ld VLD)
__global__ __launch_bounds__(256) void vtrans(const bf16* __restrict__ vh_src,
                                              const bf16* __restrict__ vl_src,
                                              bf16* __restrict__ vth,
                                              bf16* __restrict__ vtl) {
    __shared__ short T[64][72];
    const int tid = threadIdx.x;
    const int st = blockIdx.x;   // 16 s-tiles of 64
    const int bh = blockIdx.y;   // 128
    const int b = bh >> 3, h = bh & 7;
    const int sr = tid >> 2, dq = (tid & 3) * 16;
    const int s_g = st * 64 + sr;
    const int od = tid >> 3;          // 0..31 (+32)
    const int osq = (tid & 7) * 8;    // 0..56
#pragma unroll
    for (int p = 0; p < 2; ++p) {
        const short* src = (const short*)(p ? vl_src : vh_src);
        short* dst = (short*)(p ? vtl : vth);
        short8 a0 = {0, 0, 0, 0, 0, 0, 0, 0};
        short8 a1 = {0, 0, 0, 0, 0, 0, 0, 0};
        if (s_g < SEQ) {
            const short* sp = src + (size_t)(b * SEQ + s_g) * 1536 + 1024 + h * 64 + dq;
            a0 = *(const short8*)sp;
            a1 = *(const short8*)(sp + 8);
        }
        __syncthreads();
#pragma unroll
        for (int j = 0; j < 8; ++j) T[dq + j][sr] = a0[j];
#pragma unroll
        for (int j = 0; j < 8; ++j) T[dq + 8 + j][sr] = a1[j];
        __syncthreads();
        const int scol = st * 64 + osq;
        if (scol + 8 <= VLD) {
            const short8 o0 = *(const short8*)&T[od][osq];
            const short8 o1 = *(const short8*)&T[od + 32][osq];
            *(short8*)(dst + (size_t)(bh * 64 + od) * VLD + scol) = o0;
            *(short8*)(dst + (size_t)(bh * 64 + od + 32) * VLD + scol) = o1;
        }
    }
}

// ---------------------------------------------------------------- MFMA flash attention (split bf16)
__global__ __launch_bounds__(256) void attn_mfma(const bf16* __restrict__ qkh,
                                                 const bf16* __restrict__ qkl,
                                                 const bf16* __restrict__ vth,
                                                 const bf16* __restrict__ vtl,
                                                 bf16* __restrict__ chi,
                                                 bf16* __restrict__ clo) {
    __shared__ short QPs[2][64][72];   // Q staging, then P
    __shared__ short Ks[2][64][72];
    __shared__ short Vs[2][64][72];    // Vt tile: [d][n]
    const int tid = threadIdx.x;
    const int qt = blockIdx.x, bh = blockIdx.y;
    const int b = bh >> 3, h = bh & 7;
    const int wave = tid >> 6, lane = tid & 63;
    const int lm = lane & 15, g = lane >> 4, q8 = g * 8;
    const int wq = wave * 16;
    const int r0 = tid >> 2, kq = (tid & 3) * 16;
    const short8 z = {0, 0, 0, 0, 0, 0, 0, 0};

    {
        const int q = qt * 64 + r0;
        short8 a0 = z, a1 = z, b0 = z, b1 = z;
        if (q < SEQ) {
            const size_t base = (size_t)(b * SEQ + q) * 1536 + h * 64 + kq;
            a0 = *(const short8*)((const short*)qkh + base);
            a1 = *(const short8*)((const short*)qkh + base + 8);
            b0 = *(const short8*)((const short*)qkl + base);
            b1 = *(const short8*)((const short*)qkl + base + 8);
        }
        *(short8*)&QPs[0][r0][kq] = a0; *(short8*)&QPs[0][r0][kq + 8] = a1;
        *(short8*)&QPs[1][r0][kq] = b0; *(short8*)&QPs[1][r0][kq + 8] = b1;
    }
    __syncthreads();
    short8 qfh[2], qfl[2];
#pragma unroll
    for (int t = 0; t < 2; ++t) {
        qfh[t] = *(const short8*)&QPs[0][wq + lm][t * 32 + q8];
        qfl[t] = *(const short8*)&QPs[1][wq + lm][t * 32 + q8];
    }

    float m_i[4] = {-3e38f, -3e38f, -3e38f, -3e38f};
    float l_i[4] = {0.f, 0.f, 0.f, 0.f};
    f32x4 o[4];
#pragma unroll
    for (int dt = 0; dt < 4; ++dt) o[dt] = (f32x4){0.f, 0.f, 0.f, 0.f};

    // K/V staging registers (prefetched one tile ahead)
    short8 ka0 = z, ka1 = z, kl0 = z, kl1 = z;
    short8 va0 = z, va1 = z, vl0 = z, vl1 = z;
    auto loadKV = [&](int kb2) {
        const int kr = kb2 + r0;
        ka0 = z; ka1 = z; kl0 = z; kl1 = z;
        if (kr < SEQ) {
            const size_t base = (size_t)(b * SEQ + kr) * 1536 + 512 + h * 64 + kq;
            ka0 = *(const short8*)((const short*)qkh + base);
            ka1 = *(const short8*)((const short*)qkh + base + 8);
            kl0 = *(const short8*)((const short*)qkl + base);
            kl1 = *(const short8*)((const short*)qkl + base + 8);
        }
        const size_t vbase = (size_t)(bh * 64 + r0) * VLD + kb2 + kq;
        va0 = z; va1 = z; vl0 = z; vl1 = z;
        if (kb2 + kq + 8 <= VLD) {
            va0 = *(const short8*)((const short*)vth + vbase);
            vl0 = *(const short8*)((const short*)vtl + vbase);
        }
        if (kb2 + kq + 16 <= VLD) {
            va1 = *(const short8*)((const short*)vth + vbase + 8);
            vl1 = *(const short8*)((const short*)vtl + vbase + 8);
        }
    };
    loadKV(0);

    for (int kb = 0; kb < SEQ; kb += 64) {
        __syncthreads();
        {
            *(short8*)&Ks[0][r0][kq] = ka0; *(short8*)&Ks[0][r0][kq + 8] = ka1;
            *(short8*)&Ks[1][r0][kq] = kl0; *(short8*)&Ks[1][r0][kq + 8] = kl1;
            *(short8*)&Vs[0][r0][kq] = va0; *(short8*)&Vs[0][r0][kq + 8] = va1;
            *(short8*)&Vs[1][r0][kq] = vl0; *(short8*)&Vs[1][r0][kq + 8] = vl1;
        }
        __syncthreads();
        if (kb + 64 < SEQ) loadKV(kb + 64);   // prefetch: overlaps QK^T + softmax
        f32x4 sac[4];
#pragma unroll
        for (int j = 0; j < 4; ++j) sac[j] = (f32x4){0.f, 0.f, 0.f, 0.f};
#pragma unroll
        for (int t = 0; t < 2; ++t) {
#pragma unroll
            for (int j = 0; j < 4; ++j) {
                const short8 kh = *(const short8*)&Ks[0][j * 16 + lm][t * 32 + q8];
                const short8 kl = *(const short8*)&Ks[1][j * 16 + lm][t * 32 + q8];
                sac[j] = __builtin_amdgcn_mfma_f32_16x16x32_bf16(qfh[t], kh, sac[j], 0, 0, 0);
                sac[j] = __builtin_amdgcn_mfma_f32_16x16x32_bf16(qfh[t], kl, sac[j], 0, 0, 0);
                sac[j] = __builtin_amdgcn_mfma_f32_16x16x32_bf16(qfl[t], kh, sac[j], 0, 0, 0);
            }
        }
        float alpha_v[4];
#pragma unroll
        for (int reg = 0; reg < 4; ++reg) {
            float sv[4];
            float rm = -3e38f;
#pragma unroll
            for (int j = 0; j < 4; ++j) {
                const int kc = kb + j * 16 + lm;
                float s = sac[j][reg] * 0.125f;
                s = (kc < SEQ) ? s : -3e38f;
                sv[j] = s;
                rm = fmaxf(rm, s);
            }
#pragma unroll
            for (int m = 1; m < 16; m <<= 1) rm = fmaxf(rm, __shfl_xor(rm, m));
            const float mn = fmaxf(m_i[reg], rm);
            const float al = expf(m_i[reg] - mn);
            float rs = 0.f;
            const int prow = wq + g * 4 + reg;
#pragma unroll
            for (int j = 0; j < 4; ++j) {
                const float pv = expf(sv[j] - mn);
                rs += pv;
                bf16 phb = __float2bfloat16(pv);
                bf16 plb = __float2bfloat16(pv - __bfloat162float(phb));
                QPs[0][prow][j * 16 + lm] = *reinterpret_cast<short*>(&phb);
                QPs[1][prow][j * 16 + lm] = *reinterpret_cast<short*>(&plb);
            }
#pragma unroll
            for (int m = 1; m < 16; m <<= 1) rs += __shfl_xor(rs, m);
            l_i[reg] = l_i[reg] * al + rs;
            m_i[reg] = mn;
            alpha_v[reg] = al;
        }
        const f32x4 av = {alpha_v[0], alpha_v[1], alpha_v[2], alpha_v[3]};
#pragma unroll
        for (int dt = 0; dt < 4; ++dt) o[dt] *= av;
        __syncthreads();
#pragma unroll
        for (int t = 0; t < 2; ++t) {
            const short8 ph = *(const short8*)&QPs[0][wq + lm][t * 32 + q8];
            const short8 pl = *(const short8*)&QPs[1][wq + lm][t * 32 + q8];
#pragma unroll
            for (int dt = 0; dt < 4; ++dt) {
                const short8 vh = *(const short8*)&Vs[0][dt * 16 + lm][t * 32 + q8];
                const short8 vl = *(const short8*)&Vs[1][dt * 16 + lm][t * 32 + q8];
                o[dt] = __builtin_amdgcn_mfma_f32_16x16x32_bf16(ph, vh, o[dt], 0, 0, 0);
                o[dt] = __builtin_amdgcn_mfma_f32_16x16x32_bf16(ph, vl, o[dt], 0, 0, 0);
                o[dt] = __builtin_amdgcn_mfma_f32_16x16x32_bf16(pl, vh, o[dt], 0, 0, 0);
            }
        }
    }
#pragma unroll
    for (int reg = 0; reg < 4; ++reg) {
        const int q = qt * 64 + wq + g * 4 + reg;
        if (q < SEQ) {
            const float inv = 1.0f / l_i[reg];
#pragma unroll
            for (int dt = 0; dt < 4; ++dt) {
                const size_t idx = (size_t)(b * SEQ + q) * E + h * 64 + dt * 16 + lm;
                split_store(o[dt][reg] * inv, chi, clo, idx);
            }
        }
    }
}

// ---------------------------------------------------------------- codebook row norms
__global__ __launch_bounds__(256) void cbnorm_kernel(const float* __restrict__ cb,
                                                     float* __restrict__ out) {
    const int lane = threadIdx.x & 63;
    const int row = blockIdx.x * 4 + (threadIdx.x >> 6);
    const float* p = cb + (size_t)row * E;
    const float4 v0 = *(const float4*)(p + lane * 4);
    const float4 v1 = *(const float4*)(p + 256 + lane * 4);
    float sq = v0.x * v0.x + v0.y * v0.y + v0.z * v0.z + v0.w * v0.w
             + v1.x * v1.x + v1.y * v1.y + v1.z * v1.z + v1.w * v1.w;
#pragma unroll
    for (int m = 1; m < 64; m <<= 1) sq += __shfl_xor(sq, m);
    if (lane == 0) out[row] = sq;
}

// ---------------------------------------------------------------- stage A: split-bf16 MFMA distance, A-in-registers (resident)
// 250 blocks x 512 threads (8 waves = 4 row-groups x 2 col-halves; 2 waves/SIMD).
// IDENTICAL to the R6 kernel (430us, VGPR=96) except __launch_bounds__(512, 2):
// declares 2 waves/EU -> 256-VGPR/wave budget so the allocator keeps
// a_h[16]/a_l[16] (128 VGPRs) RESIDENT. R6 evidence for the spill: VGPR=96
// < 128 needed, WRITE_SIZE 4.3->22MB (A spill-stores to scratch).
// W (cb planes) streams through a 32KB LDS double buffer, counted vmcnt(2).
// part[row] = (v1, idx1, v2, idx2)
__global__ __launch_bounds__(512, 2) void argmin_mfma(
    const bf16* __restrict__ Ah, const bf16* __restrict__ Al,
    const bf16* __restrict__ Wh, const bf16* __restrict__ Wl,
    const float* __restrict__ cbn, float4* __restrict__ part) {
    __shared__ __align__(16) short Wreg[2][8192];   // 32 KB: [buf][(plane*128+col)*32]
    const int tid = threadIdx.x;
    const int rowBase = blockIdx.x * 64;
    const int wave = tid >> 6, lane = tid & 63;
    const int rowg = wave & 3;        // 16-row group
    const int chalf = wave >> 2;      // 64-col half (j offset 0 / 4)
    const int lm = lane & 15, g = lane >> 4;
    const int g8 = g * 8;
    const int psl8 = (g ^ ((lm >> 1) & 3)) * 8;
    const int sslot = (lane & 3) ^ ((lane >> 3) & 3);
    const int srow = lane >> 2;
    const int row = rowBase + rowg * 16 + lm;   // the A row this lane's frags cover

    // ---- A -> registers (once): 16 k-chunks x 2 planes, 16B frag each.
    short8 a_h[16], a_l[16];
#pragma unroll
    for (int c = 0; c < 16; ++c) {
        a_h[c] = *(const short8*)(Ah + (size_t)row * E + c * 32 + g8);
        a_l[c] = *(const short8*)(Al + (size_t)row * E + c * 32 + g8);
    }
    // pin: opaque redefinition forbids rematerializing the loads
#pragma unroll
    for (int c = 0; c < 16; ++c) {
        asm volatile("" : "+v"(a_h[c]));
        asm volatile("" : "+v"(a_l[c]));
    }

    // ---- W staging: tile s (ct = s>>4 col-tile, k = s&15) -> buf s&1.
    // 16 pieces of 1KB; 8 waves stage 2 each -> vmcnt granularity = 2/wave.
    auto stageW = [&](int s) {
        const int ct = s >> 4, k = s & 15;
        const int colB = ct * 128;
        short* dstb = &Wreg[s & 1][0];
#pragma unroll
        for (int e = 0; e < 2; ++e) {
            const int m = wave * 2 + e;   // 0..15
            const int p = m >> 3;         // plane
            const int j = m & 7;          // 16-col group
            const bf16* srcp = p ? Wl : Wh;
            gll16(srcp + (size_t)(colB + j * 16 + srow) * E + k * 32 + sslot * 8,
                  dstb + ((p * 128 + j * 16) * 32));
        }
    };
    stageW(0);
    stageW(1);

    float rv1[4], rv2[4];
    int rc1[4], rc2[4];
#pragma unroll
    for (int r = 0; r < 4; ++r) {
        rv1[r] = 3e38f; rv2[r] = 3e38f;
        rc1[r] = 0x7fffffff; rc2[r] = 0x7fffffff;
    }
    f32x4 acc[4];
#pragma unroll
    for (int j = 0; j < 4; ++j) acc[j] = (f32x4){0.f, 0.f, 0.f, 0.f};

    for (int ct = 0; ct < 32; ++ct) {
        const int colB = ct * 128;
#pragma unroll
        for (int k = 0; k < 16; ++k) {      // full unroll: a_h[k]/a_l[k] static
            const int s = ct * 16 + k;
            if (s + 1 < 512) asm volatile("s_waitcnt vmcnt(2)" ::: "memory");
            else             asm volatile("s_waitcnt vmcnt(0)" ::: "memory");
            __builtin_amdgcn_s_barrier();
            __builtin_amdgcn_sched_barrier(0);
            const short* B = &Wreg[s & 1][0];
#pragma unroll
            for (int j = 0; j < 4; ++j) {
                const int jj = chalf * 4 + j;
                const short8 wh = *(const short8*)(B + (jj * 16 + lm) * 32 + psl8);
                const short8 wl = *(const short8*)(B + (128 + jj * 16 + lm) * 32 + psl8);
                acc[j] = __builtin_amdgcn_mfma_f32_16x16x32_bf16(a_h[k], wh, acc[j], 0, 0, 0);
                acc[j] = __builtin_amdgcn_mfma_f32_16x16x32_bf16(a_h[k], wl, acc[j], 0, 0, 0);
                acc[j] = __builtin_amdgcn_mfma_f32_16x16x32_bf16(a_l[k], wh, acc[j], 0, 0, 0);
            }
            __builtin_amdgcn_s_barrier();     // all waves done reading Wreg[s&1]
            if (s + 2 < 512) stageW(s + 2);   // refill Wreg[s&1] with tile s+2
        }
        // ct finished: fold this wave's 64 cols into per-lane running top2
#pragma unroll
        for (int j = 0; j < 4; ++j) {
            const int col = colB + (chalf * 4 + j) * 16 + lm;
            const float nv = cbn[col];
#pragma unroll
            for (int r = 0; r < 4; ++r) {
                const float d = nv - 2.0f * acc[j][r];
                t2_ins(d, col, rv1[r], rc1[r], rv2[r], rc2[r]);
            }
            acc[j] = (f32x4){0.f, 0.f, 0.f, 0.f};
        }
    }

    // ---- merge across the 16 lm lanes of each g group
#pragma unroll
    for (int r = 0; r < 4; ++r) {
#pragma unroll
        for (int m = 1; m < 16; m <<= 1) {
            const float w1 = __shfl_xor(rv1[r], m); const int d1 = __shfl_xor(rc1[r], m);
            const float w2 = __shfl_xor(rv2[r], m); const int d2 = __shfl_xor(rc2[r], m);
            t2_ins(w1, d1, rv1[r], rc1[r], rv2[r], rc2[r]);
            t2_ins(w2, d2, rv1[r], rc1[r], rv2[r], rc2[r]);
        }
    }
    // ---- cross-half merge via dead W LDS (no DMA in flight: last stage guarded)
    __syncthreads();
    float4* mbuf = reinterpret_cast<float4*>(&Wreg[0][0]);  // [64 rows][2 halves]
    if (lm == 0) {
#pragma unroll
        for (int r = 0; r < 4; ++r)
            mbuf[(rowg * 16 + g * 4 + r) * 2 + chalf] =
                make_float4(rv1[r], (float)rc1[r], rv2[r], (float)rc2[r]);
    }
    __syncthreads();
    if (tid < 64) {
        const float4 p0 = mbuf[tid * 2 + 0];
        const float4 p1 = mbuf[tid * 2 + 1];
        float v1 = p0.x, v2 = p0.z;
        int c1 = (int)p0.y, c2 = (int)p0.w;
        t2_ins(p1.x, (int)p1.y, v1, c1, v2, c2);
        t2_ins(p1.z, (int)p1.w, v1, c1, v2, c2);
        part[rowBase + tid] = make_float4(v1, (float)c1, v2, (float)c2);
    }
}

// ---------------------------------------------------------------- stage B: exact fp32 rescore of top2
__global__ __launch_bounds__(256) void argmin_exact(const float4* __restrict__ part,
                                                    const float* __restrict__ fc,
                                                    const float* __restrict__ cb,
                                                    const float* __restrict__ cbn,
                                                    float* __restrict__ tokf) {
    const int wave = threadIdx.x >> 6, lane = threadIdx.x & 63;
    const int r = blockIdx.x * 4 + wave;   // 4000 blocks
    const float4 p = part[r];
    const int c1 = (int)p.y;
    const int c2 = (int)p.w;
    // exact fp32 d2 for c1, c2
    const float* fr = fc + (size_t)r * E + lane * 8;
    const float* p1 = cb + (size_t)c1 * E + lane * 8;
    const float* p2 = cb + (size_t)c2 * E + lane * 8;
    float d1 = 0.f, d2 = 0.f;
#pragma unroll
    for (int j = 0; j < 8; ++j) {
        const float f = fr[j];
        d1 += f * p1[j];
        d2 += f * p2[j];
    }
#pragma unroll
    for (int m = 1; m < 64; m <<= 1) {
        d1 += __shfl_xor(d1, m);
        d2 += __shfl_xor(d2, m);
    }
    d1 = cbn[c1] - 2.0f * d1;
    d2 = cbn[c2] - 2.0f * d2;
    const int win = ((d1 < d2) || (d1 == d2 && c1 < c2)) ? c1 : c2;
    if (lane == 0) tokf[r] = (float)win;
}

// ---------------------------------------------------------------- launch
extern "C" void kernel_launch(void* const* d_in, const int* in_sizes, int n_in,
                              void* d_out, int out_size, void* d_ws, size_t ws_size,
                              hipStream_t stream) {
    const int* noisy = (const int*)d_in[0];
    const float* codebook = (const float*)d_in[1];
    const float* pos_enc = (const float*)d_in[2];
    const float* qkv_w = (const float*)d_in[3];
    const float* qkv_b = (const float*)d_in[4];
    const float* out_w = (const float*)d_in[5];
    const float* out_b = (const float*)d_in[6];
    const float* ln1_g = (const float*)d_in[7];
    const float* ln1_b = (const float*)d_in[8];
    const float* ln2_g = (const float*)d_in[9];
    const float* ln2_b = (const float*)d_in[10];
    const float* ff1_w = (const float*)d_in[11];
    const float* ff1_b = (const float*)d_in[12];
    const float* ff2_w = (const float*)d_in[13];
    const float* ff2_b = (const float*)d_in[14];
    const float* fin_g = (const float*)d_in[15];
    const float* fin_b = (const float*)d_in[16];
    const float* pp1_w = (const float*)d_in[17];
    const float* pp1_b = (const float*)d_in[18];
    const float* pp_ln_g = (const float*)d_in[19];
    const float* pp_ln_b = (const float*)d_in[20];
    const float* pp2_w = (const float*)d_in[21];
    const float* pp2_b = (const float*)d_in[22];
    const float* res_w = (const float*)d_in[23];
    const float* fc1_w = (const float*)d_in[24];
    const float* fc1_b = (const float*)d_in[25];
    const float* fc_ln_g = (const float*)d_in[26];
    const float* fc_ln_b = (const float*)d_in[27];
    const float* fc2_w = (const float*)d_in[28];
    const float* fc2_b = (const float*)d_in[29];

    // workspace (floats), total 41,025,536 floats = 164.1 MB
    float* ws = (float*)d_ws;
    float* y = ws;                        // [0, 8.192M)
    float* REG = ws + 8192000;            // [8.192M, 32.768M)
    bf16* qkvh = (bf16*)REG;              // 16000x1536 shorts
    bf16* qkvl = qkvh + 24576000;
    bf16* mid_hi = (bf16*)REG;            // FF phase: 16000x1024
    bf16* mid_lo = mid_hi + 16384000;
    float* slotA = REG;                   // tail: e planes / fc fp32
    float* slotB = REG + 8192000;         // tail: pp1/fc1 fp32 tmp, then cbn+partials
    bf16* e_hi = (bf16*)slotA;
    bf16* e_lo = e_hi + 8192000;
    bf16* fcp2_hi = (bf16*)(REG + 16384000);  // fc planes (spare tail region)
    bf16* fcp2_lo = fcp2_hi + 8192000;
    float* WV = ws + 32768000;            // [32.768M, 41.0255M): Vt planes OR weight splits OR cb planes
    bf16* vth = (bf16*)WV;                // 8192 x VLD
    bf16* vtl = vth + 8192 * VLD;
    bf16* wA_hi = (bf16*)WV;              // cap 2048x512 each
    bf16* wA_lo = wA_hi + 1048576;
    bf16* wB_hi = wA_lo + 1048576;
    bf16* wB_lo = wB_hi + 1048576;
    bf16* cbh = wB_lo + 1048576;          // 4096x512, after weights (tail only)
    bf16* cbl = cbh + 2097152;
    float* cbn = slotB;                   // tail-only
    float4* part = (float4*)(slotB + 4096);  // 16000 float4
    // h planes live in d_out (dead before final outputs are written)
    bf16* h_hi = (bf16*)d_out;
    bf16* h_lo = h_hi + 8192000;
    float* tokf = (float*)d_out + 8192000;

    const dim3 blk(256);
    const dim3 g512(4, 125), g1024(8, 125), g1536(12, 125);

    embed_kernel<<<dim3(NTOK), dim3(128), 0, stream>>>(noisy, codebook, pos_enc, y);

    for (int l = 0; l < 4; ++l) {
        ln_planes<0><<<dim3(4000), blk, 0, stream>>>(y, h_hi, h_lo, ln1_g + l * E, ln1_b + l * E);
        split_w<<<dim3(3072), blk, 0, stream>>>(qkv_w + (size_t)l * 1536 * E, E, 9, 1536 * E, wA_hi, wA_lo);
        gemm_split<4><<<g1536, blk, 0, stream>>>(
            h_hi, h_lo, E, wA_hi, wA_lo, E, qkv_b + (size_t)l * 1536,
            nullptr, 0, qkvh, qkvl, 1536, nullptr, nullptr, nullptr, nullptr, E);
        vtrans<<<dim3(16, 128), blk, 0, stream>>>(qkvh, qkvl, vth, vtl);  // overwrites wA (dead)
        attn_mfma<<<dim3(16, 128), blk, 0, stream>>>(qkvh, qkvl, vth, vtl, h_hi, h_lo);
        split_w<<<dim3(1024), blk, 0, stream>>>(out_w + (size_t)l * E * E, E, 9, E * E, wB_hi, wB_lo);
        gemm_split<1><<<g512, blk, 0, stream>>>(
            h_hi, h_lo, E, wB_hi, wB_lo, E, out_b + (size_t)l * E,
            y, E, nullptr, nullptr, 0, nullptr, nullptr, nullptr, nullptr, E);
        ln_planes<0><<<dim3(4000), blk, 0, stream>>>(y, h_hi, h_lo, ln2_g + l * E, ln2_b + l * E);
        split_w<<<dim3(4096), blk, 0, stream>>>(ff1_w + (size_t)l * FFD * E, E, 9, FFD * E, wA_hi, wA_lo);
        split_w<<<dim3(4096), blk, 0, stream>>>(ff2_w + (size_t)l * E * FFD, FFD, 11, E * FFD, wB_hi, wB_lo);
        for (int c = 0; c < 2; ++c) {
            gemm_split<2><<<g1024, blk, 0, stream>>>(
                h_hi, h_lo, E, wA_hi + (size_t)c * 1024 * E, wA_lo + (size_t)c * 1024 * E, E,
                ff1_b + (size_t)l * FFD + c * 1024,
                nullptr, 0, mid_hi, mid_lo, 1024, nullptr, nullptr, nullptr, nullptr, E);
            gemm_split<1><<<g512, blk, 0, stream>>>(
                mid_hi, mid_lo, 1024, wB_hi + c * 1024, wB_lo + c * 1024, FFD,
                (c == 0) ? (ff2_b + (size_t)l * E) : nullptr,
                y, E, nullptr, nullptr, 0, nullptr, nullptr, nullptr, nullptr, 1024);
        }
    }

    // tail
    ln_planes<0><<<dim3(4000), blk, 0, stream>>>(y, h_hi, h_lo, fin_g, fin_b);
    split_w<<<dim3(1024), blk, 0, stream>>>(pp1_w, E, 9, E * E, wA_hi, wA_lo);
    gemm_split<0><<<g512, blk, 0, stream>>>(
        h_hi, h_lo, E, wA_hi, wA_lo, E, pp1_b,
        slotB, E, nullptr, nullptr, 0, nullptr, nullptr, nullptr, nullptr, E);
    ln_planes<1><<<dim3(4000), blk, 0, stream>>>(slotB, h_hi, h_lo, pp_ln_g, pp_ln_b);
    split_w<<<dim3(1024), blk, 0, stream>>>(pp2_w, E, 9, E * E, wB_hi, wB_lo);
    gemm_split<3><<<g512, blk, 0, stream>>>(
        h_hi, h_lo, E, wB_hi, wB_lo, E, pp2_b,
        nullptr, 0, e_hi, e_lo, E, noisy, codebook, pos_enc, res_w, E);
    split_w<<<dim3(1024), blk, 0, stream>>>(fc1_w, E, 9, E * E, wA_hi, wA_lo);
    gemm_split<0><<<g512, blk, 0, stream>>>(
        e_hi, e_lo, E, wA_hi, wA_lo, E, fc1_b,
        slotB, E, nullptr, nullptr, 0, nullptr, nullptr, nullptr, nullptr, E);
    ln_planes<1><<<dim3(4000), blk, 0, stream>>>(slotB, h_hi, h_lo, fc_ln_g, fc_ln_b);
    split_w<<<dim3(1024), blk, 0, stream>>>(fc2_w, E, 9, E * E, wB_hi, wB_lo);
    gemm_split<5><<<g512, blk, 0, stream>>>(
        h_hi, h_lo, E, wB_hi, wB_lo, E, fc2_b,
        slotA, E, fcp2_hi, fcp2_lo, E, nullptr, nullptr, nullptr, nullptr, E);  // fc fp32 + planes

    // argmin: A-in-registers (resident) MFMA top2 + exact fp32 rescore
    split_w<<<dim3(8192), blk, 0, stream>>>(codebook, E, 9, CBN * E, cbh, cbl);
    cbnorm_kernel<<<dim3(1024), blk, 0, stream>>>(codebook, cbn);
    argmin_mfma<<<dim3(250), dim3(512), 0, stream>>>(fcp2_hi, fcp2_lo, cbh, cbl, cbn, part);
    argmin_exact<<<dim3(4000), blk, 0, stream>>>(part, slotA, codebook, cbn, tokf);
    hipMemcpyAsync(d_out, slotA, (size_t)8192000 * 4, hipMemcpyDeviceToDevice, stream);
}